// Round 17
// baseline (476.130 us; speedup 1.0000x reference)
//
#include <hip/hip_runtime.h>

typedef _Float16 f16;
typedef f16 f16x8 __attribute__((ext_vector_type(8)));
typedef float f32x16 __attribute__((ext_vector_type(16)));

#define NB 2
#define NC 1152
#define NHW 4096
#define NCH3 3456
#define NC2 2304

#define LO_SCALE 2048.0f
#define LO_INV (1.0f / 2048.0f)

// ===== Channel permutation =====
// Permuted row p = role*1152 + g*8 + r  <->  original channel c = g*24 + role*8 + r
// q-role rows are p < 1152 -> contiguous; fp32-fidelity split applies there only.
// qkv, ms stored permuted and in f16.

__device__ __align__(16) f16 g_Wcat_h[(size_t)NCH3 * NC];
__device__ __align__(16) f16 g_Wcat_l[(size_t)NC * NC];
__device__ __align__(16) f16 g_WoutB_h[(size_t)NC * NC2];
__device__ __align__(16) f16 g_XT_h[(size_t)NB * NHW * NC];
__device__ __align__(16) f16 g_XT_l[(size_t)NB * NHW * NC];
__device__ __align__(16) f16 g_qkv[(size_t)NB * NCH3 * NHW];
__device__ __align__(16) f16 g_ms[(size_t)NB * NCH3 * NHW];
__device__ __align__(16) f16 g_attnT_h[(size_t)NB * NHW * NC2];
__device__ float g_part[NB * NHW];

__device__ __forceinline__ void gload16(const void* g, void* l) {
  __builtin_amdgcn_global_load_lds(
      (const __attribute__((address_space(1))) unsigned int*)g,
      (__attribute__((address_space(3))) unsigned int*)l, 16, 0, 0);
}

__device__ __forceinline__ void split_f16(float v, f16& h, f16& l) {
  h = (f16)v;
  l = (f16)((v - (float)h) * LO_SCALE);
}

// ---------- weight conversion (role-permuted rows) ----------
__global__ __launch_bounds__(256) void convert_weights(
    const float* __restrict__ wq, const float* __restrict__ wk,
    const float* __restrict__ wv, const float* __restrict__ wout) {
  size_t idx = ((size_t)blockIdx.x * 256 + threadIdx.x) * 4;
  const size_t NWC = (size_t)NCH3 * NC;
  const size_t NWO = (size_t)NC * NC2;
  if (idx < NWC) {
    int p = (int)(idx / NC);
    int kk = (int)(idx % NC);
    int role = p / 1152, w = p % 1152;
    int g = w >> 3, r = w & 7;
    int c = g * 24 + role * 8 + r;
    const float* src = (c < 1152) ? wq + (size_t)c * NC + kk
                      : (c < 2304) ? wk + (size_t)(c - 1152) * NC + kk
                                   : wv + (size_t)(c - 2304) * NC + kk;
    if (p < 1152) {
#pragma unroll
      for (int j = 0; j < 4; ++j)
        split_f16(src[j], g_Wcat_h[idx + j], g_Wcat_l[idx + j]);
    } else {
#pragma unroll
      for (int j = 0; j < 4; ++j) g_Wcat_h[idx + j] = (f16)src[j];
    }
  } else {
    size_t k = idx - NWC;
    if (k < NWO) {
      const float* src = wout + k;
#pragma unroll
      for (int j = 0; j < 4; ++j) g_WoutB_h[k + j] = (f16)src[j];
    }
  }
}

// ---------- x (B,C,HW) fp32 -> XT (B,HW,C) scaled-split f16 ----------
__global__ __launch_bounds__(256) void transpose_x(const float* __restrict__ x) {
  __shared__ float tile[32][33];
  int z = blockIdx.z;
  int p0 = blockIdx.x * 32, c0 = blockIdx.y * 32;
  int tx = threadIdx.x, ty = threadIdx.y;
#pragma unroll
  for (int i = 0; i < 32; i += 8)
    tile[ty + i][tx] = x[((size_t)z * NC + c0 + ty + i) * NHW + p0 + tx];
  __syncthreads();
#pragma unroll
  for (int i = 0; i < 32; i += 8) {
    size_t o = ((size_t)z * NHW + p0 + ty + i) * NC + c0 + tx;
    split_f16(tile[tx][ty + i], g_XT_h[o], g_XT_l[o]);
  }
}

// ===== gemm1 split part (q-role, fp32 fidelity): 2-phase depth-3, 128x256 =====
__global__ __launch_bounds__(512, 1) void gemm1s_kernel() {
  __shared__ __align__(16) char smem[147456];
  int bid = blockIdx.x;
  int swz = (bid & 7) * 36 + (bid >> 3);  // 288 blocks
  int bx = swz % 9, rem = swz / 9;
  int bm = bx * 128, bn = (rem & 15) * 256, bz = rem >> 4;

  const int tid = threadIdx.x;
  const int lane = tid & 63;
  const int wid = tid >> 6;
  const int wr = wid >> 2, wc = wid & 3;
  const size_t boff = (size_t)bz * ((size_t)NHW * NC);
  const f16* Bh = g_XT_h + boff;
  const f16* Bl = g_XT_l + boff;
  f16* Cb = g_qkv + (size_t)bz * ((size_t)NCH3 * NHW);
  const int srow = tid >> 2;
  const int skb = (((tid & 3) ^ ((srow >> 1) & 3)) * 8);
  const f16* gAh = g_Wcat_h + (size_t)(bm + srow) * NC + skb;
  const f16* gAl = g_Wcat_l + (size_t)(bm + srow) * NC + skb;
  const f16* gBh0 = Bh + (size_t)(bn + srow) * NC + skb;
  const f16* gBl0 = Bl + (size_t)(bn + srow) * NC + skb;
  const f16* gBh1 = Bh + (size_t)(bn + 128 + srow) * NC + skb;
  const f16* gBl1 = Bl + (size_t)(bn + 128 + srow) * NC + skb;
  const int ldso = tid * 16;

  f32x16 acc[2][2] = {};
  f32x16 acc2[2][2] = {};
  const int r31 = lane & 31;
  const int key = (r31 >> 1) & 3;
  const int kblk = lane >> 5;

#define BUF(b, off) (smem + (b) * 49152 + (off))
#define STAGE_S(buf, tile)                                      \
  do {                                                          \
    size_t ko = (size_t)(tile) * 32;                            \
    gload16(gAh + ko, BUF(buf, 0) + ldso);                      \
    gload16(gAl + ko, BUF(buf, 8192) + ldso);                   \
    gload16(gBh0 + ko, BUF(buf, 16384) + ldso);                 \
    gload16(gBh1 + ko, BUF(buf, 24576) + ldso);                 \
    gload16(gBl0 + ko, BUF(buf, 32768) + ldso);                 \
    gload16(gBl1 + ko, BUF(buf, 40960) + ldso);                 \
  } while (0)

#define COMPUTE_S(buf)                                                         \
  do {                                                                         \
    const f16* sAh = (const f16*)BUF(buf, 0);                                  \
    const f16* sAl = (const f16*)BUF(buf, 8192);                               \
    const f16* sBh = (const f16*)BUF(buf, 16384);                              \
    const f16* sBl = (const f16*)BUF(buf, 32768);                              \
    _Pragma("unroll") for (int kh = 0; kh < 2; ++kh) {                         \
      const int bsw = ((kh * 2 + kblk) ^ key) * 8;                             \
      f16x8 ah[2], al[2], bh[2], bl[2];                                        \
      _Pragma("unroll") for (int mb = 0; mb < 2; ++mb) {                       \
        int ro = (wr * 64 + mb * 32 + r31) * 32 + bsw;                         \
        ah[mb] = *(const f16x8*)(sAh + ro);                                    \
        al[mb] = *(const f16x8*)(sAl + ro);                                    \
      }                                                                        \
      _Pragma("unroll") for (int nb = 0; nb < 2; ++nb) {                       \
        int ro = (wc * 64 + nb * 32 + r31) * 32 + bsw;                         \
        bh[nb] = *(const f16x8*)(sBh + ro);                                    \
        bl[nb] = *(const f16x8*)(sBl + ro);                                    \
      }                                                                        \
      __builtin_amdgcn_s_setprio(1);                                           \
      _Pragma("unroll") for (int mb = 0; mb < 2; ++mb)                         \
        _Pragma("unroll") for (int nb = 0; nb < 2; ++nb) {                     \
          acc[mb][nb]  = __builtin_amdgcn_mfma_f32_32x32x16_f16(ah[mb], bh[nb], acc[mb][nb], 0, 0, 0);  \
          acc2[mb][nb] = __builtin_amdgcn_mfma_f32_32x32x16_f16(ah[mb], bl[nb], acc2[mb][nb], 0, 0, 0); \
          acc2[mb][nb] = __builtin_amdgcn_mfma_f32_32x32x16_f16(al[mb], bh[nb], acc2[mb][nb], 0, 0, 0); \
        }                                                                      \
      __builtin_amdgcn_s_setprio(0);                                           \
    }                                                                          \
  } while (0)

  const int NT = NC / 32;  // 36
  STAGE_S(0, 0);
  STAGE_S(1, 1);
  int cb = 0, sb = 2;
#pragma unroll 1
  for (int t = 0; t < NT - 1; ++t) {
    asm volatile("s_waitcnt vmcnt(6)" ::: "memory");
    __builtin_amdgcn_s_barrier();
    __builtin_amdgcn_sched_barrier(0);
    if (t + 2 < NT) STAGE_S(sb, t + 2);
    COMPUTE_S(cb);
    __builtin_amdgcn_sched_barrier(0);
    __builtin_amdgcn_s_barrier();
    cb = (cb == 2) ? 0 : cb + 1;
    sb = (sb == 2) ? 0 : sb + 1;
  }
  asm volatile("s_waitcnt vmcnt(0)" ::: "memory");
  __builtin_amdgcn_s_barrier();
  __builtin_amdgcn_sched_barrier(0);
  COMPUTE_S(cb);
#undef STAGE_S
#undef COMPUTE_S
#undef BUF
#pragma unroll
  for (int mb = 0; mb < 2; ++mb)
#pragma unroll
    for (int nb = 0; nb < 2; ++nb) {
      int col = bn + wc * 64 + nb * 32 + r31;
#pragma unroll
      for (int reg = 0; reg < 16; ++reg) {
        int row = bm + wr * 64 + mb * 32 + (reg & 3) + 8 * (reg >> 2) + 4 * (lane >> 5);
        Cb[(size_t)row * NHW + col] = (f16)(acc[mb][nb][reg] + acc2[mb][nb][reg] * LO_INV);
      }
    }
}

// ===== gemm1 plain part (k,v-role): 256x256 tile, BK=32, 3-buffer deep
// pipeline. tile t reads buf[t%3]; tile t+2 staged into buf[(t+2)%3] —
// never the buffer being read or the next one -> no WAR race.
// One barrier per K-tile; counted vmcnt(4); per-phase stage||ds_read||MFMA.
__global__ __launch_bounds__(512, 1) void gemm1p_kernel() {
  __shared__ __align__(16) f16 sA[3][256 * 32];
  __shared__ __align__(16) f16 sB[3][256 * 32];
  int bid = blockIdx.x;
  int swz = (bid & 7) * 36 + (bid >> 3);  // 288 blocks
  int bx = swz % 9, rem = swz / 9;
  int bmG = 1152 + bx * 256;
  int bn = (rem & 15) * 256;
  int bz = rem >> 4;

  const int tid = threadIdx.x;
  const int lane = tid & 63;
  const int wid = tid >> 6;
  const int wr = wid >> 2, wc = wid & 3;  // 2m x 4n waves, wave tile 128x64
  const f16* Bb = g_XT_h + (size_t)bz * ((size_t)NHW * NC);
  f16* Cb = g_qkv + (size_t)bz * ((size_t)NCH3 * NHW);
  const int srow = tid >> 2;
  const int skb = (((tid & 3) ^ ((srow >> 1) & 3)) * 8);
  const f16* gA0 = g_Wcat_h + (size_t)(bmG + srow) * NC + skb;
  const f16* gA1 = g_Wcat_h + (size_t)(bmG + 128 + srow) * NC + skb;
  const f16* gB0 = Bb + (size_t)(bn + srow) * NC + skb;
  const f16* gB1 = Bb + (size_t)(bn + 128 + srow) * NC + skb;
  const int ldso = tid * 16;

  f32x16 acc[4][2] = {};
  const int r31 = lane & 31;
  const int key = (r31 >> 1) & 3;
  const int kblk = lane >> 5;

#define STG_A(buf, tile)                                        \
  do {                                                          \
    size_t ko = (size_t)(tile) * 32;                            \
    gload16(gA0 + ko, (char*)sA[buf] + ldso);                   \
    gload16(gA1 + ko, (char*)sA[buf] + 8192 + ldso);            \
  } while (0)
#define STG_B(buf, tile)                                        \
  do {                                                          \
    size_t ko = (size_t)(tile) * 32;                            \
    gload16(gB0 + ko, (char*)sB[buf] + ldso);                   \
    gload16(gB1 + ko, (char*)sB[buf] + 8192 + ldso);            \
  } while (0)

#define FPHASE(buf, ks, STG)                                                   \
  do {                                                                         \
    STG;                                                                       \
    const int bsw = ((ks) * 2 + kblk) * 8;                                     \
    f16x8 af[4], bf[2];                                                        \
    _Pragma("unroll") for (int ma = 0; ma < 4; ++ma) {                         \
      int row = wr * 128 + ma * 32 + r31;                                      \
      af[ma] = *(const f16x8*)(sA[buf] + row * 32 + ((bsw >> 3) ^ key) * 8);   \
    }                                                                          \
    _Pragma("unroll") for (int nb = 0; nb < 2; ++nb) {                         \
      int row = wc * 64 + nb * 32 + r31;                                       \
      bf[nb] = *(const f16x8*)(sB[buf] + row * 32 + ((bsw >> 3) ^ key) * 8);   \
    }                                                                          \
    __builtin_amdgcn_s_setprio(1);                                             \
    _Pragma("unroll") for (int ma = 0; ma < 4; ++ma)                           \
      _Pragma("unroll") for (int nb = 0; nb < 2; ++nb)                         \
        acc[ma][nb] = __builtin_amdgcn_mfma_f32_32x32x16_f16(af[ma], bf[nb], acc[ma][nb], 0, 0, 0); \
    __builtin_amdgcn_s_setprio(0);                                             \
  } while (0)

  const int NT = NC / 32;  // 36
  STG_A(0, 0); STG_B(0, 0);
  STG_A(1, 1); STG_B(1, 1);
  int cb = 0;
#pragma unroll 1
  for (int t = 0; t < NT - 2; ++t) {
    asm volatile("s_waitcnt vmcnt(4)" ::: "memory");
    __builtin_amdgcn_s_barrier();
    int pb = cb + 2; if (pb >= 3) pb -= 3;
    FPHASE(cb, 0, STG_A(pb, t + 2));
    FPHASE(cb, 1, STG_B(pb, t + 2));
    cb = (cb == 2) ? 0 : cb + 1;
  }
  // t = NT-2: tile's data ready when all but newest 4 (tile NT-1's) landed
  asm volatile("s_waitcnt vmcnt(4)" ::: "memory");
  __builtin_amdgcn_s_barrier();
  FPHASE(cb, 0, (void)0);
  FPHASE(cb, 1, (void)0);
  cb = (cb == 2) ? 0 : cb + 1;
  // t = NT-1: drain everything
  asm volatile("s_waitcnt vmcnt(0)" ::: "memory");
  __builtin_amdgcn_s_barrier();
  FPHASE(cb, 0, (void)0);
  FPHASE(cb, 1, (void)0);
#undef STG_A
#undef STG_B
#undef FPHASE
#pragma unroll
  for (int ma = 0; ma < 4; ++ma)
#pragma unroll
    for (int nb = 0; nb < 2; ++nb) {
      int col = bn + wc * 64 + nb * 32 + r31;
#pragma unroll
      for (int reg = 0; reg < 16; ++reg) {
        int row = bmG + wr * 128 + ma * 32 + (reg & 3) + 8 * (reg >> 2) + 4 * (lane >> 5);
        Cb[(size_t)row * NHW + col] = (f16)acc[ma][nb][reg];
      }
    }
}

// ---------- gemm2: plain f16 (128x128, 4 waves) + fused RMS epilogue ----------
template <int M, int N, int K>
__device__ __forceinline__ void gemm_body_plain(
    const f16* __restrict__ A, const f16* __restrict__ Bt,
    float* __restrict__ C, int bm, int bn, int bz) {
  __shared__ __align__(16) f16 sA[3][128 * 32];
  __shared__ __align__(16) f16 sB[3][128 * 32];
  const int tid = threadIdx.x;
  const int lane = tid & 63;
  const int wid = tid >> 6;
  const int wr = wid >> 1, wc = wid & 1;
  const f16* Bb = Bt + (size_t)bz * ((size_t)N * K);
  float* Cb = C + (size_t)bz * ((size_t)M * N);
  const int srow = tid >> 2;
  const int skb = (((tid & 3) ^ ((srow >> 1) & 3)) * 8);
  const f16* gA0 = A + (size_t)(bm + srow) * K + skb;
  const f16* gA1 = A + (size_t)(bm + 64 + srow) * K + skb;
  const f16* gB0 = Bb + (size_t)(bn + srow) * K + skb;
  const f16* gB1 = Bb + (size_t)(bn + 64 + srow) * K + skb;
  const int ldso = tid * 16;

  f32x16 acc[2][2] = {};
  const int r31 = lane & 31;
  const int key = (r31 >> 1) & 3;
  const int kblk = lane >> 5;

#define STAGE_P(buf, tile)                              \
  do {                                                  \
    size_t ko = (size_t)(tile) * 32;                    \
    gload16(gA0 + ko, (char*)sA[buf] + ldso);           \
    gload16(gA1 + ko, (char*)sA[buf] + 4096 + ldso);    \
    gload16(gB0 + ko, (char*)sB[buf] + ldso);           \
    gload16(gB1 + ko, (char*)sB[buf] + 4096 + ldso);    \
  } while (0)

#define COMPUTE_P(buf)                                                         \
  do {                                                                         \
    _Pragma("unroll") for (int kh = 0; kh < 2; ++kh) {                         \
      const int bsw = ((kh * 2 + kblk) ^ key) * 8;                             \
      f16x8 af[2], bf[2];                                                      \
      _Pragma("unroll") for (int mb = 0; mb < 2; ++mb)                         \
        af[mb] = *(const f16x8*)(sA[buf] + (wr * 64 + mb * 32 + r31) * 32 + bsw); \
      _Pragma("unroll") for (int nb = 0; nb < 2; ++nb)                         \
        bf[nb] = *(const f16x8*)(sB[buf] + (wc * 64 + nb * 32 + r31) * 32 + bsw); \
      __builtin_amdgcn_s_setprio(1);                                           \
      _Pragma("unroll") for (int mb = 0; mb < 2; ++mb)                         \
        _Pragma("unroll") for (int nb = 0; nb < 2; ++nb)                       \
          acc[mb][nb] = __builtin_amdgcn_mfma_f32_32x32x16_f16(af[mb], bf[nb], acc[mb][nb], 0, 0, 0); \
      __builtin_amdgcn_s_setprio(0);                                           \
    }                                                                          \
  } while (0)

  const int NT = K / 32;  // 72
  STAGE_P(0, 0);
  STAGE_P(1, 1);
  int cb = 0, sb = 2;
#pragma unroll 1
  for (int t = 0; t < NT - 1; ++t) {
    asm volatile("s_waitcnt vmcnt(4)" ::: "memory");
    __builtin_amdgcn_s_barrier();
    __builtin_amdgcn_sched_barrier(0);
    if (t + 2 < NT) STAGE_P(sb, t + 2);
    COMPUTE_P(cb);
    __builtin_amdgcn_sched_barrier(0);
    __builtin_amdgcn_s_barrier();
    cb = (cb == 2) ? 0 : cb + 1;
    sb = (sb == 2) ? 0 : sb + 1;
  }
  asm volatile("s_waitcnt vmcnt(0)" ::: "memory");
  __builtin_amdgcn_s_barrier();
  __builtin_amdgcn_sched_barrier(0);
  COMPUTE_P(cb);
#undef STAGE_P
#undef COMPUTE_P
#pragma unroll
  for (int nb = 0; nb < 2; ++nb) {
    int col = bn + wc * 64 + nb * 32 + r31;
    float csum = 0.f;
#pragma unroll
    for (int mb = 0; mb < 2; ++mb)
#pragma unroll
      for (int reg = 0; reg < 16; ++reg) {
        int row = bm + wr * 64 + mb * 32 + (reg & 3) + 8 * (reg >> 2) + 4 * (lane >> 5);
        float v = acc[mb][nb][reg];
        Cb[(size_t)row * N + col] = v;
        csum += v * v;
      }
    atomicAdd(&g_part[bz * NHW + col], csum);
  }
}

__global__ __launch_bounds__(256, 2) void gemm2_kernel(float* __restrict__ out) {
  int bid = blockIdx.x;
  int swz = (bid & 7) * (576 / 8) + (bid >> 3);
  int bx = swz % 9, rem = swz / 9;
  int by = rem & 31, bz = rem >> 5;
  gemm_body_plain<NC, NHW, NC2>(g_WoutB_h, g_attnT_h, out,
                                bx * 128, by * 128, bz);
}

// ---------- fused depthwise 5x5 + grouped 1x1 (f16 io, fp32 math, 8 px/thr) ----------
__global__ __launch_bounds__(256) void conv_kernel(const float* __restrict__ wdw,
                                                   const float* __restrict__ wpw) {
  const int z = blockIdx.z, gg = blockIdx.y;  // 0..431
  const int pbase = (gg % 3) * 1152 + (gg / 3) * 8;
  const int px = blockIdx.x * 2048 + threadIdx.x * 8;
  const int h = px >> 6, w0 = px & 63;
  const f16* base = g_qkv + ((size_t)z * NCH3 + pbase) * NHW;

  float dw[8][8];
#pragma unroll
  for (int ci = 0; ci < 8; ++ci) {
    const float* wd = wdw + (gg * 8 + ci) * 25;
    const f16* srcc = base + (size_t)ci * NHW;
    float acc[8] = {};
#pragma unroll
    for (int dy = -2; dy <= 2; ++dy) {
      int hh = h + dy;
      if (hh < 0 || hh > 63) continue;
      const f16* row = srcc + hh * 64;
      f16x8 Lv = {}, Rv = {};
      if (w0 >= 8) Lv = *(const f16x8*)(row + w0 - 8);
      f16x8 Mv = *(const f16x8*)(row + w0);
      if (w0 <= 48) Rv = *(const f16x8*)(row + w0 + 8);
      float c[24];
#pragma unroll
      for (int i = 0; i < 8; ++i) {
        c[i] = (float)Lv[i];
        c[8 + i] = (float)Mv[i];
        c[16 + i] = (float)Rv[i];
      }
      const float* wrow = wd + (dy + 2) * 5;
#pragma unroll
      for (int dx = 0; dx < 5; ++dx) {
        float wv = wrow[dx];
#pragma unroll
        for (int j = 0; j < 8; ++j) acc[j] += c[6 + j + dx] * wv;
      }
    }
#pragma unroll
    for (int j = 0; j < 8; ++j) dw[ci][j] = acc[j];
  }
#pragma unroll
  for (int o = 0; o < 8; ++o) {
    const float* wp = wpw + (size_t)(gg * 8 + o) * 8;
    float out[8] = {};
#pragma unroll
    for (int i = 0; i < 8; ++i) {
      float wv = wp[i];
#pragma unroll
      for (int j = 0; j < 8; ++j) out[j] += wv * dw[i][j];
    }
    f16x8 ov;
#pragma unroll
    for (int j = 0; j < 8; ++j) ov[j] = (f16)out[j];
    *(f16x8*)(g_ms + ((size_t)z * NCH3 + pbase + o) * NHW + px) = ov;
  }
}

// ---------- linear attention per (group, batch): f16 reads, 8 px/thread ----------
__global__ __launch_bounds__(256) void attn_kernel() {
  int g = blockIdx.x;
  int z = blockIdx.y;
  int tid = threadIdx.x;
  const f16* buf = (g < 144) ? g_qkv : g_ms;
  int gq = (g < 144) ? g : g - 144;
  const f16* qp = buf + ((size_t)z * NCH3 + gq * 8) * NHW;
  const f16* kp = buf + ((size_t)z * NCH3 + 1152 + gq * 8) * NHW;
  const f16* vp = buf + ((size_t)z * NCH3 + 2304 + gq * 8) * NHW;

  float s[9][8];
#pragma unroll
  for (int d = 0; d < 9; ++d)
#pragma unroll
    for (int e = 0; e < 8; ++e) s[d][e] = 0.f;

  for (int p0 = tid * 8; p0 < NHW; p0 += 2048) {
    f16x8 kx[8], vx[8];
#pragma unroll
    for (int e = 0; e < 8; ++e) kx[e] = *(const f16x8*)(kp + (size_t)e * NHW + p0);
#pragma unroll
    for (int d = 0; d < 8; ++d) vx[d] = *(const f16x8*)(vp + (size_t)d * NHW + p0);
#pragma unroll
    for (int j = 0; j < 8; ++j) {
      float kv[8], vv[8];
#pragma unroll
      for (int e = 0; e < 8; ++e) kv[e] = fmaxf((float)kx[e][j], 0.f);
#pragma unroll
      for (int d = 0; d < 8; ++d) vv[d] = (float)vx[d][j];
#pragma unroll
      for (int e = 0; e < 8; ++e) {
#pragma unroll
        for (int d = 0; d < 8; ++d) s[d][e] += vv[d] * kv[e];
        s[8][e] += kv[e];
      }
    }
  }
#pragma unroll
  for (int d = 0; d < 9; ++d)
#pragma unroll
    for (int e = 0; e < 8; ++e) {
      float v = s[d][e];
#pragma unroll
      for (int off = 32; off > 0; off >>= 1) v += __shfl_xor(v, off, 64);
      s[d][e] = v;
    }
  __shared__ float sred[4][72];
  __shared__ float sc[72];
  int w = tid >> 6, lane = tid & 63;
  if (lane == 0) {
#pragma unroll
    for (int d = 0; d < 9; ++d)
#pragma unroll
      for (int e = 0; e < 8; ++e) sred[w][d * 8 + e] = s[d][e];
  }
  __syncthreads();
  if (tid < 72) sc[tid] = sred[0][tid] + sred[1][tid] + sred[2][tid] + sred[3][tid];
  __syncthreads();
  float scl[9][8];
#pragma unroll
  for (int d = 0; d < 9; ++d)
#pragma unroll
    for (int e = 0; e < 8; ++e) scl[d][e] = sc[d * 8 + e];

  for (int p0 = tid * 8; p0 < NHW; p0 += 2048) {
    f16x8 qx[8];
#pragma unroll
    for (int e = 0; e < 8; ++e) qx[e] = *(const f16x8*)(qp + (size_t)e * NHW + p0);
#pragma unroll
    for (int j = 0; j < 8; ++j) {
      float qv[8];
#pragma unroll
      for (int e = 0; e < 8; ++e) qv[e] = fmaxf((float)qx[e][j], 0.f);
      float o[9];
#pragma unroll
      for (int d = 0; d < 9; ++d) {
        float a = 0.f;
#pragma unroll
        for (int e = 0; e < 8; ++e) a += scl[d][e] * qv[e];
        o[d] = a;
      }
      float r = 1.f / (o[8] + 1e-15f);
      f16x8 oh;
#pragma unroll
      for (int d = 0; d < 8; ++d) oh[d] = (f16)(o[d] * r);
      *(f16x8*)(g_attnT_h + ((size_t)z * NHW + p0 + j) * NC2 + g * 8) = oh;
    }
  }
}

// ---------- RMSNorm (partial sums fused into gemm2 epilogue) ----------
__global__ __launch_bounds__(256) void rms_zero() {
  g_part[blockIdx.x * 256 + threadIdx.x] = 0.f;
}
__global__ __launch_bounds__(256) void rms_norm(float* __restrict__ y,
                                                const float* __restrict__ w,
                                                const float* __restrict__ b) {
  size_t i = ((size_t)blockIdx.x * 256 + threadIdx.x) * 4;
  float4 v = *(const float4*)(y + i);
  int p = (int)(i & (NHW - 1));
  int c = (int)((i >> 12) % NC);
  int z = (int)(i / ((size_t)NC * NHW));
  const float inv = 1.0f / NC;
  float wc = w[c], bc = b[c];
  const float* pp = &g_part[z * NHW + p];
  v.x = v.x * rsqrtf(pp[0] * inv + 1e-5f) * wc + bc;
  v.y = v.y * rsqrtf(pp[1] * inv + 1e-5f) * wc + bc;
  v.z = v.z * rsqrtf(pp[2] * inv + 1e-5f) * wc + bc;
  v.w = v.w * rsqrtf(pp[3] * inv + 1e-5f) * wc + bc;
  *(float4*)(y + i) = v;
}

extern "C" void kernel_launch(void* const* d_in, const int* in_sizes, int n_in,
                              void* d_out, int out_size, void* d_ws, size_t ws_size,
                              hipStream_t stream) {
  const float* x = (const float*)d_in[0];
  const float* wq = (const float*)d_in[1];
  const float* wk = (const float*)d_in[2];
  const float* wv = (const float*)d_in[3];
  const float* wdw = (const float*)d_in[4];
  const float* wpw = (const float*)d_in[5];
  const float* wout = (const float*)d_in[6];
  const float* rw = (const float*)d_in[7];
  const float* rb = (const float*)d_in[8];
  float* y = (float*)d_out;

  convert_weights<<<6480, 256, 0, stream>>>(wq, wk, wv, wout);
  transpose_x<<<dim3(128, 36, 2), dim3(32, 8), 0, stream>>>(x);
  gemm1s_kernel<<<288, 512, 0, stream>>>();
  gemm1p_kernel<<<288, 512, 0, stream>>>();
  conv_kernel<<<dim3(2, 432, 2), 256, 0, stream>>>(wdw, wpw);
  attn_kernel<<<dim3(288, 2), 256, 0, stream>>>();
  rms_zero<<<32, 256, 0, stream>>>();
  gemm2_kernel<<<576, 256, 0, stream>>>(y);
  rms_norm<<<9216, 256, 0, stream>>>(y, rw, rb);
}

// Round 18
// 438.064 us; speedup vs baseline: 1.0869x; 1.0869x over previous
//
#include <hip/hip_runtime.h>

typedef _Float16 f16;
typedef f16 f16x8 __attribute__((ext_vector_type(8)));
typedef float f32x16 __attribute__((ext_vector_type(16)));

#define NB 2
#define NC 1152
#define NHW 4096
#define NCH3 3456
#define NC2 2304

#define LO_SCALE 2048.0f
#define LO_INV (1.0f / 2048.0f)

// ===== Channel permutation =====
// Permuted row p = role*1152 + g*8 + r  <->  original channel c = g*24 + role*8 + r
// q-role rows are p < 1152 -> contiguous; fp32-fidelity split applies there only.
// qkv, ms stored permuted and in f16.

__device__ __align__(16) f16 g_Wcat_h[(size_t)NCH3 * NC];
__device__ __align__(16) f16 g_Wcat_l[(size_t)NC * NC];
__device__ __align__(16) f16 g_WoutB_h[(size_t)NC * NC2];
__device__ __align__(16) f16 g_XT_h[(size_t)NB * NHW * NC];
__device__ __align__(16) f16 g_XT_l[(size_t)NB * NHW * NC];
__device__ __align__(16) f16 g_qkv[(size_t)NB * NCH3 * NHW];
__device__ __align__(16) f16 g_ms[(size_t)NB * NCH3 * NHW];
__device__ __align__(16) f16 g_attnT_h[(size_t)NB * NHW * NC2];
__device__ float g_part[NB * NHW];

__device__ __forceinline__ void gload16(const void* g, void* l) {
  __builtin_amdgcn_global_load_lds(
      (const __attribute__((address_space(1))) unsigned int*)g,
      (__attribute__((address_space(3))) unsigned int*)l, 16, 0, 0);
}

__device__ __forceinline__ void split_f16(float v, f16& h, f16& l) {
  h = (f16)v;
  l = (f16)((v - (float)h) * LO_SCALE);
}

// ---------- weight conversion (role-permuted rows) ----------
__global__ __launch_bounds__(256) void convert_weights(
    const float* __restrict__ wq, const float* __restrict__ wk,
    const float* __restrict__ wv, const float* __restrict__ wout) {
  size_t idx = ((size_t)blockIdx.x * 256 + threadIdx.x) * 4;
  const size_t NWC = (size_t)NCH3 * NC;
  const size_t NWO = (size_t)NC * NC2;
  if (idx < NWC) {
    int p = (int)(idx / NC);
    int kk = (int)(idx % NC);
    int role = p / 1152, w = p % 1152;
    int g = w >> 3, r = w & 7;
    int c = g * 24 + role * 8 + r;
    const float* src = (c < 1152) ? wq + (size_t)c * NC + kk
                      : (c < 2304) ? wk + (size_t)(c - 1152) * NC + kk
                                   : wv + (size_t)(c - 2304) * NC + kk;
    if (p < 1152) {
#pragma unroll
      for (int j = 0; j < 4; ++j)
        split_f16(src[j], g_Wcat_h[idx + j], g_Wcat_l[idx + j]);
    } else {
#pragma unroll
      for (int j = 0; j < 4; ++j) g_Wcat_h[idx + j] = (f16)src[j];
    }
  } else {
    size_t k = idx - NWC;
    if (k < NWO) {
      const float* src = wout + k;
#pragma unroll
      for (int j = 0; j < 4; ++j) g_WoutB_h[k + j] = (f16)src[j];
    }
  }
}

// ---------- x (B,C,HW) fp32 -> XT (B,HW,C) scaled-split f16 ----------
__global__ __launch_bounds__(256) void transpose_x(const float* __restrict__ x) {
  __shared__ float tile[32][33];
  int z = blockIdx.z;
  int p0 = blockIdx.x * 32, c0 = blockIdx.y * 32;
  int tx = threadIdx.x, ty = threadIdx.y;
#pragma unroll
  for (int i = 0; i < 32; i += 8)
    tile[ty + i][tx] = x[((size_t)z * NC + c0 + ty + i) * NHW + p0 + tx];
  __syncthreads();
#pragma unroll
  for (int i = 0; i < 32; i += 8) {
    size_t o = ((size_t)z * NHW + p0 + ty + i) * NC + c0 + tx;
    split_f16(tile[tx][ty + i], g_XT_h[o], g_XT_l[o]);
  }
}

// ===== gemm1 q-part (split-f16, fp32 fidelity): 128x256, deep 3-buf,
// one barrier per K-tile, counted vmcnt(6) (6 loads/tile, 2 tiles in flight).
__device__ __forceinline__ void gemm1_split_deep(char* smem, int bm, int bn, int bz) {
  const int tid = threadIdx.x;
  const int lane = tid & 63;
  const int wid = tid >> 6;
  const int wr = wid >> 2, wc = wid & 3;
  const size_t boff = (size_t)bz * ((size_t)NHW * NC);
  const f16* Bh = g_XT_h + boff;
  const f16* Bl = g_XT_l + boff;
  f16* Cb = g_qkv + (size_t)bz * ((size_t)NCH3 * NHW);
  const int srow = tid >> 2;
  const int skb = (((tid & 3) ^ ((srow >> 1) & 3)) * 8);
  const f16* gAh = g_Wcat_h + (size_t)(bm + srow) * NC + skb;
  const f16* gAl = g_Wcat_l + (size_t)(bm + srow) * NC + skb;
  const f16* gBh0 = Bh + (size_t)(bn + srow) * NC + skb;
  const f16* gBl0 = Bl + (size_t)(bn + srow) * NC + skb;
  const f16* gBh1 = Bh + (size_t)(bn + 128 + srow) * NC + skb;
  const f16* gBl1 = Bl + (size_t)(bn + 128 + srow) * NC + skb;
  const int ldso = tid * 16;

  f32x16 acc[2][2] = {};
  f32x16 acc2[2][2] = {};
  const int r31 = lane & 31;
  const int key = (r31 >> 1) & 3;
  const int kblk = lane >> 5;

#define BUFS(b, off) (smem + (b) * 49152 + (off))
#define STG_S0(buf, tile)                                       \
  do {                                                          \
    size_t ko = (size_t)(tile) * 32;                            \
    gload16(gAh + ko, BUFS(buf, 0) + ldso);                     \
    gload16(gAl + ko, BUFS(buf, 8192) + ldso);                  \
    gload16(gBh0 + ko, BUFS(buf, 16384) + ldso);                \
  } while (0)
#define STG_S1(buf, tile)                                       \
  do {                                                          \
    size_t ko = (size_t)(tile) * 32;                            \
    gload16(gBh1 + ko, BUFS(buf, 24576) + ldso);                \
    gload16(gBl0 + ko, BUFS(buf, 32768) + ldso);                \
    gload16(gBl1 + ko, BUFS(buf, 40960) + ldso);                \
  } while (0)

#define FPH_S(buf, kh, STG)                                                    \
  do {                                                                         \
    STG;                                                                       \
    const int bsw = (((kh) * 2 + kblk) ^ key) * 8;                             \
    const f16* sAh = (const f16*)BUFS(buf, 0);                                 \
    const f16* sAl = (const f16*)BUFS(buf, 8192);                              \
    const f16* sBh = (const f16*)BUFS(buf, 16384);                             \
    const f16* sBl = (const f16*)BUFS(buf, 32768);                             \
    f16x8 ah[2], al[2], bh[2], bl[2];                                          \
    _Pragma("unroll") for (int mb = 0; mb < 2; ++mb) {                         \
      int ro = (wr * 64 + mb * 32 + r31) * 32 + bsw;                           \
      ah[mb] = *(const f16x8*)(sAh + ro);                                      \
      al[mb] = *(const f16x8*)(sAl + ro);                                      \
    }                                                                          \
    _Pragma("unroll") for (int nb = 0; nb < 2; ++nb) {                         \
      int ro = (wc * 64 + nb * 32 + r31) * 32 + bsw;                           \
      bh[nb] = *(const f16x8*)(sBh + ro);                                      \
      bl[nb] = *(const f16x8*)(sBl + ro);                                      \
    }                                                                          \
    __builtin_amdgcn_s_setprio(1);                                             \
    _Pragma("unroll") for (int mb = 0; mb < 2; ++mb)                           \
      _Pragma("unroll") for (int nb = 0; nb < 2; ++nb) {                       \
        acc[mb][nb]  = __builtin_amdgcn_mfma_f32_32x32x16_f16(ah[mb], bh[nb], acc[mb][nb], 0, 0, 0);  \
        acc2[mb][nb] = __builtin_amdgcn_mfma_f32_32x32x16_f16(ah[mb], bl[nb], acc2[mb][nb], 0, 0, 0); \
        acc2[mb][nb] = __builtin_amdgcn_mfma_f32_32x32x16_f16(al[mb], bh[nb], acc2[mb][nb], 0, 0, 0); \
      }                                                                        \
    __builtin_amdgcn_s_setprio(0);                                             \
  } while (0)

  const int NT = NC / 32;  // 36
  STG_S0(0, 0); STG_S1(0, 0);
  STG_S0(1, 1); STG_S1(1, 1);
  int cb = 0;
#pragma unroll 1
  for (int t = 0; t < NT - 2; ++t) {
    asm volatile("s_waitcnt vmcnt(6)" ::: "memory");
    __builtin_amdgcn_s_barrier();
    int pb = cb + 2; if (pb >= 3) pb -= 3;
    FPH_S(cb, 0, STG_S0(pb, t + 2));
    FPH_S(cb, 1, STG_S1(pb, t + 2));
    cb = (cb == 2) ? 0 : cb + 1;
  }
  asm volatile("s_waitcnt vmcnt(6)" ::: "memory");
  __builtin_amdgcn_s_barrier();
  FPH_S(cb, 0, (void)0);
  FPH_S(cb, 1, (void)0);
  cb = (cb == 2) ? 0 : cb + 1;
  asm volatile("s_waitcnt vmcnt(0)" ::: "memory");
  __builtin_amdgcn_s_barrier();
  FPH_S(cb, 0, (void)0);
  FPH_S(cb, 1, (void)0);
#undef STG_S0
#undef STG_S1
#undef FPH_S
#undef BUFS
#pragma unroll
  for (int mb = 0; mb < 2; ++mb)
#pragma unroll
    for (int nb = 0; nb < 2; ++nb) {
      int col = bn + wc * 64 + nb * 32 + r31;
#pragma unroll
      for (int reg = 0; reg < 16; ++reg) {
        int row = bm + wr * 64 + mb * 32 + (reg & 3) + 8 * (reg >> 2) + 4 * (lane >> 5);
        Cb[(size_t)row * NHW + col] = (f16)(acc[mb][nb][reg] + acc2[mb][nb][reg] * LO_INV);
      }
    }
}

// ===== gemm1 kv-part (plain f16): 256x256, deep 3-buf, vmcnt(4) (round-17 proven)
__device__ __forceinline__ void gemm1_plain_deep(char* smem, int bmG, int bn, int bz) {
  f16* sA0 = (f16*)smem;                 // 3 x 16KB
  f16* sB0 = (f16*)(smem + 49152);       // 3 x 16KB
  const int tid = threadIdx.x;
  const int lane = tid & 63;
  const int wid = tid >> 6;
  const int wr = wid >> 2, wc = wid & 3;  // wave tile 128x64
  const f16* Bb = g_XT_h + (size_t)bz * ((size_t)NHW * NC);
  f16* Cb = g_qkv + (size_t)bz * ((size_t)NCH3 * NHW);
  const int srow = tid >> 2;
  const int skb = (((tid & 3) ^ ((srow >> 1) & 3)) * 8);
  const f16* gA0 = g_Wcat_h + (size_t)(bmG + srow) * NC + skb;
  const f16* gA1 = g_Wcat_h + (size_t)(bmG + 128 + srow) * NC + skb;
  const f16* gB0 = Bb + (size_t)(bn + srow) * NC + skb;
  const f16* gB1 = Bb + (size_t)(bn + 128 + srow) * NC + skb;
  const int ldso = tid * 16;

  f32x16 acc[4][2] = {};
  const int r31 = lane & 31;
  const int key = (r31 >> 1) & 3;
  const int kblk = lane >> 5;

#define SA(b) (sA0 + (b) * 8192)
#define SB(b) (sB0 + (b) * 8192)
#define STG_A(buf, tile)                                        \
  do {                                                          \
    size_t ko = (size_t)(tile) * 32;                            \
    gload16(gA0 + ko, (char*)SA(buf) + ldso);                   \
    gload16(gA1 + ko, (char*)SA(buf) + 8192 + ldso);            \
  } while (0)
#define STG_B(buf, tile)                                        \
  do {                                                          \
    size_t ko = (size_t)(tile) * 32;                            \
    gload16(gB0 + ko, (char*)SB(buf) + ldso);                   \
    gload16(gB1 + ko, (char*)SB(buf) + 8192 + ldso);            \
  } while (0)
#define FPH_P(buf, ks, STG)                                                    \
  do {                                                                         \
    STG;                                                                       \
    const int bsw = (((ks) * 2 + kblk) ^ key) * 8;                             \
    f16x8 af[4], bf[2];                                                        \
    _Pragma("unroll") for (int ma = 0; ma < 4; ++ma) {                         \
      int row = wr * 128 + ma * 32 + r31;                                      \
      af[ma] = *(const f16x8*)(SA(buf) + row * 32 + bsw);                      \
    }                                                                          \
    _Pragma("unroll") for (int nb = 0; nb < 2; ++nb) {                         \
      int row = wc * 64 + nb * 32 + r31;                                       \
      bf[nb] = *(const f16x8*)(SB(buf) + row * 32 + bsw);                      \
    }                                                                          \
    __builtin_amdgcn_s_setprio(1);                                             \
    _Pragma("unroll") for (int ma = 0; ma < 4; ++ma)                           \
      _Pragma("unroll") for (int nb = 0; nb < 2; ++nb)                         \
        acc[ma][nb] = __builtin_amdgcn_mfma_f32_32x32x16_f16(af[ma], bf[nb], acc[ma][nb], 0, 0, 0); \
    __builtin_amdgcn_s_setprio(0);                                             \
  } while (0)

  // NOTE: sA rows are [256][32] with the same 16B-block swizzle as staging.
  const int NT = NC / 32;  // 36
  STG_A(0, 0); STG_B(0, 0);
  STG_A(1, 1); STG_B(1, 1);
  int cb = 0;
#pragma unroll 1
  for (int t = 0; t < NT - 2; ++t) {
    asm volatile("s_waitcnt vmcnt(4)" ::: "memory");
    __builtin_amdgcn_s_barrier();
    int pb = cb + 2; if (pb >= 3) pb -= 3;
    FPH_P(cb, 0, STG_A(pb, t + 2));
    FPH_P(cb, 1, STG_B(pb, t + 2));
    cb = (cb == 2) ? 0 : cb + 1;
  }
  asm volatile("s_waitcnt vmcnt(4)" ::: "memory");
  __builtin_amdgcn_s_barrier();
  FPH_P(cb, 0, (void)0);
  FPH_P(cb, 1, (void)0);
  cb = (cb == 2) ? 0 : cb + 1;
  asm volatile("s_waitcnt vmcnt(0)" ::: "memory");
  __builtin_amdgcn_s_barrier();
  FPH_P(cb, 0, (void)0);
  FPH_P(cb, 1, (void)0);
#undef STG_A
#undef STG_B
#undef FPH_P
#undef SA
#undef SB
#pragma unroll
  for (int ma = 0; ma < 4; ++ma)
#pragma unroll
    for (int nb = 0; nb < 2; ++nb) {
      int col = bn + wc * 64 + nb * 32 + r31;
#pragma unroll
      for (int reg = 0; reg < 16; ++reg) {
        int row = bmG + wr * 128 + ma * 32 + (reg & 3) + 8 * (reg >> 2) + 4 * (lane >> 5);
        Cb[(size_t)row * NHW + col] = (f16)acc[ma][nb][reg];
      }
    }
}

__global__ __launch_bounds__(512, 1) void gemm1_kernel() {
  __shared__ __align__(16) char smem[147456];
  int bid = blockIdx.x;
  int swz = (bid & 7) * 72 + (bid >> 3);  // 576 blocks, 576 % 8 == 0
  if (swz < 288) {
    int bx = swz % 9, rem = swz / 9;
    gemm1_split_deep(smem, bx * 128, (rem & 15) * 256, rem >> 4);
  } else {
    int w2 = swz - 288;
    int bx = w2 % 9, rem = w2 / 9;
    gemm1_plain_deep(smem, 1152 + bx * 256, (rem & 15) * 256, rem >> 4);
  }
}

// ---------- gemm2: plain f16 128x128, deep 3-buf, vmcnt(4), fused RMS epilogue ----------
__global__ __launch_bounds__(256, 2) void gemm2_kernel(float* __restrict__ out) {
  __shared__ __align__(16) f16 sA[3][128 * 32];
  __shared__ __align__(16) f16 sB[3][128 * 32];
  int bid = blockIdx.x;
  int swz = (bid & 7) * (576 / 8) + (bid >> 3);
  int bx = swz % 9, rem = swz / 9;
  int bm = bx * 128, bn = (rem & 31) * 128, bz = rem >> 5;

  const int tid = threadIdx.x;
  const int lane = tid & 63;
  const int wid = tid >> 6;
  const int wr = wid >> 1, wc = wid & 1;
  const f16* Bb = g_attnT_h + (size_t)bz * ((size_t)NHW * NC2);
  float* Cb = out + (size_t)bz * ((size_t)NC * NHW);
  const int srow = tid >> 2;
  const int skb = (((tid & 3) ^ ((srow >> 1) & 3)) * 8);
  const f16* gA0 = g_WoutB_h + (size_t)(bm + srow) * NC2 + skb;
  const f16* gA1 = g_WoutB_h + (size_t)(bm + 64 + srow) * NC2 + skb;
  const f16* gB0 = Bb + (size_t)(bn + srow) * NC2 + skb;
  const f16* gB1 = Bb + (size_t)(bn + 64 + srow) * NC2 + skb;
  const int ldso = tid * 16;

  f32x16 acc[2][2] = {};
  const int r31 = lane & 31;
  const int key = (r31 >> 1) & 3;
  const int kblk = lane >> 5;

#define STG_A2(buf, tile)                               \
  do {                                                  \
    size_t ko = (size_t)(tile) * 32;                    \
    gload16(gA0 + ko, (char*)sA[buf] + ldso);           \
    gload16(gA1 + ko, (char*)sA[buf] + 4096 + ldso);    \
  } while (0)
#define STG_B2(buf, tile)                               \
  do {                                                  \
    size_t ko = (size_t)(tile) * 32;                    \
    gload16(gB0 + ko, (char*)sB[buf] + ldso);           \
    gload16(gB1 + ko, (char*)sB[buf] + 4096 + ldso);    \
  } while (0)
#define FPH_2(buf, ks, STG)                                                    \
  do {                                                                         \
    STG;                                                                       \
    const int bsw = (((ks) * 2 + kblk) ^ key) * 8;                             \
    f16x8 af[2], bf[2];                                                        \
    _Pragma("unroll") for (int mb = 0; mb < 2; ++mb)                           \
      af[mb] = *(const f16x8*)(sA[buf] + (wr * 64 + mb * 32 + r31) * 32 + bsw);\
    _Pragma("unroll") for (int nb = 0; nb < 2; ++nb)                           \
      bf[nb] = *(const f16x8*)(sB[buf] + (wc * 64 + nb * 32 + r31) * 32 + bsw);\
    __builtin_amdgcn_s_setprio(1);                                             \
    _Pragma("unroll") for (int mb = 0; mb < 2; ++mb)                           \
      _Pragma("unroll") for (int nb = 0; nb < 2; ++nb)                         \
        acc[mb][nb] = __builtin_amdgcn_mfma_f32_32x32x16_f16(af[mb], bf[nb], acc[mb][nb], 0, 0, 0); \
    __builtin_amdgcn_s_setprio(0);                                             \
  } while (0)

  const int NT = NC2 / 32;  // 72
  STG_A2(0, 0); STG_B2(0, 0);
  STG_A2(1, 1); STG_B2(1, 1);
  int cb = 0;
#pragma unroll 1
  for (int t = 0; t < NT - 2; ++t) {
    asm volatile("s_waitcnt vmcnt(4)" ::: "memory");
    __builtin_amdgcn_s_barrier();
    int pb = cb + 2; if (pb >= 3) pb -= 3;
    FPH_2(cb, 0, STG_A2(pb, t + 2));
    FPH_2(cb, 1, STG_B2(pb, t + 2));
    cb = (cb == 2) ? 0 : cb + 1;
  }
  asm volatile("s_waitcnt vmcnt(4)" ::: "memory");
  __builtin_amdgcn_s_barrier();
  FPH_2(cb, 0, (void)0);
  FPH_2(cb, 1, (void)0);
  cb = (cb == 2) ? 0 : cb + 1;
  asm volatile("s_waitcnt vmcnt(0)" ::: "memory");
  __builtin_amdgcn_s_barrier();
  FPH_2(cb, 0, (void)0);
  FPH_2(cb, 1, (void)0);
#undef STG_A2
#undef STG_B2
#undef FPH_2
#pragma unroll
  for (int nb = 0; nb < 2; ++nb) {
    int col = bn + wc * 64 + nb * 32 + r31;
    float csum = 0.f;
#pragma unroll
    for (int mb = 0; mb < 2; ++mb)
#pragma unroll
      for (int reg = 0; reg < 16; ++reg) {
        int row = bm + wr * 64 + mb * 32 + (reg & 3) + 8 * (reg >> 2) + 4 * (lane >> 5);
        float v = acc[mb][nb][reg];
        Cb[(size_t)row * NHW + col] = v;
        csum += v * v;
      }
    atomicAdd(&g_part[bz * NHW + col], csum);
  }
}

// ---------- fused depthwise 5x5 + grouped 1x1 (f16 io, fp32 math, 8 px/thr) ----------
__global__ __launch_bounds__(256) void conv_kernel(const float* __restrict__ wdw,
                                                   const float* __restrict__ wpw) {
  const int z = blockIdx.z, gg = blockIdx.y;  // 0..431
  const int pbase = (gg % 3) * 1152 + (gg / 3) * 8;
  const int px = blockIdx.x * 2048 + threadIdx.x * 8;
  const int h = px >> 6, w0 = px & 63;
  const f16* base = g_qkv + ((size_t)z * NCH3 + pbase) * NHW;

  float dw[8][8];
#pragma unroll
  for (int ci = 0; ci < 8; ++ci) {
    const float* wd = wdw + (gg * 8 + ci) * 25;
    const f16* srcc = base + (size_t)ci * NHW;
    float acc[8] = {};
#pragma unroll
    for (int dy = -2; dy <= 2; ++dy) {
      int hh = h + dy;
      if (hh < 0 || hh > 63) continue;
      const f16* row = srcc + hh * 64;
      f16x8 Lv = {}, Rv = {};
      if (w0 >= 8) Lv = *(const f16x8*)(row + w0 - 8);
      f16x8 Mv = *(const f16x8*)(row + w0);
      if (w0 <= 48) Rv = *(const f16x8*)(row + w0 + 8);
      float c[24];
#pragma unroll
      for (int i = 0; i < 8; ++i) {
        c[i] = (float)Lv[i];
        c[8 + i] = (float)Mv[i];
        c[16 + i] = (float)Rv[i];
      }
      const float* wrow = wd + (dy + 2) * 5;
#pragma unroll
      for (int dx = 0; dx < 5; ++dx) {
        float wv = wrow[dx];
#pragma unroll
        for (int j = 0; j < 8; ++j) acc[j] += c[6 + j + dx] * wv;
      }
    }
#pragma unroll
    for (int j = 0; j < 8; ++j) dw[ci][j] = acc[j];
  }
#pragma unroll
  for (int o = 0; o < 8; ++o) {
    const float* wp = wpw + (size_t)(gg * 8 + o) * 8;
    float out[8] = {};
#pragma unroll
    for (int i = 0; i < 8; ++i) {
      float wv = wp[i];
#pragma unroll
      for (int j = 0; j < 8; ++j) out[j] += wv * dw[i][j];
    }
    f16x8 ov;
#pragma unroll
    for (int j = 0; j < 8; ++j) ov[j] = (f16)out[j];
    *(f16x8*)(g_ms + ((size_t)z * NCH3 + pbase + o) * NHW + px) = ov;
  }
}

// ---------- linear attention per (group, batch): f16 reads, 8 px/thread ----------
__global__ __launch_bounds__(256) void attn_kernel() {
  int g = blockIdx.x;
  int z = blockIdx.y;
  int tid = threadIdx.x;
  const f16* buf = (g < 144) ? g_qkv : g_ms;
  int gq = (g < 144) ? g : g - 144;
  const f16* qp = buf + ((size_t)z * NCH3 + gq * 8) * NHW;
  const f16* kp = buf + ((size_t)z * NCH3 + 1152 + gq * 8) * NHW;
  const f16* vp = buf + ((size_t)z * NCH3 + 2304 + gq * 8) * NHW;

  float s[9][8];
#pragma unroll
  for (int d = 0; d < 9; ++d)
#pragma unroll
    for (int e = 0; e < 8; ++e) s[d][e] = 0.f;

  for (int p0 = tid * 8; p0 < NHW; p0 += 2048) {
    f16x8 kx[8], vx[8];
#pragma unroll
    for (int e = 0; e < 8; ++e) kx[e] = *(const f16x8*)(kp + (size_t)e * NHW + p0);
#pragma unroll
    for (int d = 0; d < 8; ++d) vx[d] = *(const f16x8*)(vp + (size_t)d * NHW + p0);
#pragma unroll
    for (int j = 0; j < 8; ++j) {
      float kv[8], vv[8];
#pragma unroll
      for (int e = 0; e < 8; ++e) kv[e] = fmaxf((float)kx[e][j], 0.f);
#pragma unroll
      for (int d = 0; d < 8; ++d) vv[d] = (float)vx[d][j];
#pragma unroll
      for (int e = 0; e < 8; ++e) {
#pragma unroll
        for (int d = 0; d < 8; ++d) s[d][e] += vv[d] * kv[e];
        s[8][e] += kv[e];
      }
    }
  }
#pragma unroll
  for (int d = 0; d < 9; ++d)
#pragma unroll
    for (int e = 0; e < 8; ++e) {
      float v = s[d][e];
#pragma unroll
      for (int off = 32; off > 0; off >>= 1) v += __shfl_xor(v, off, 64);
      s[d][e] = v;
    }
  __shared__ float sred[4][72];
  __shared__ float sc[72];
  int w = tid >> 6, lane = tid & 63;
  if (lane == 0) {
#pragma unroll
    for (int d = 0; d < 9; ++d)
#pragma unroll
      for (int e = 0; e < 8; ++e) sred[w][d * 8 + e] = s[d][e];
  }
  __syncthreads();
  if (tid < 72) sc[tid] = sred[0][tid] + sred[1][tid] + sred[2][tid] + sred[3][tid];
  __syncthreads();
  float scl[9][8];
#pragma unroll
  for (int d = 0; d < 9; ++d)
#pragma unroll
    for (int e = 0; e < 8; ++e) scl[d][e] = sc[d * 8 + e];

  for (int p0 = tid * 8; p0 < NHW; p0 += 2048) {
    f16x8 qx[8];
#pragma unroll
    for (int e = 0; e < 8; ++e) qx[e] = *(const f16x8*)(qp + (size_t)e * NHW + p0);
#pragma unroll
    for (int j = 0; j < 8; ++j) {
      float qv[8];
#pragma unroll
      for (int e = 0; e < 8; ++e) qv[e] = fmaxf((float)qx[e][j], 0.f);
      float o[9];
#pragma unroll
      for (int d = 0; d < 9; ++d) {
        float a = 0.f;
#pragma unroll
        for (int e = 0; e < 8; ++e) a += scl[d][e] * qv[e];
        o[d] = a;
      }
      float r = 1.f / (o[8] + 1e-15f);
      f16x8 oh;
#pragma unroll
      for (int d = 0; d < 8; ++d) oh[d] = (f16)(o[d] * r);
      *(f16x8*)(g_attnT_h + ((size_t)z * NHW + p0 + j) * NC2 + g * 8) = oh;
    }
  }
}

// ---------- RMSNorm (partial sums fused into gemm2 epilogue) ----------
__global__ __launch_bounds__(256) void rms_zero() {
  g_part[blockIdx.x * 256 + threadIdx.x] = 0.f;
}
__global__ __launch_bounds__(256) void rms_norm(float* __restrict__ y,
                                                const float* __restrict__ w,
                                                const float* __restrict__ b) {
  size_t i = ((size_t)blockIdx.x * 256 + threadIdx.x) * 4;
  float4 v = *(const float4*)(y + i);
  int p = (int)(i & (NHW - 1));
  int c = (int)((i >> 12) % NC);
  int z = (int)(i / ((size_t)NC * NHW));
  const float inv = 1.0f / NC;
  float wc = w[c], bc = b[c];
  const float* pp = &g_part[z * NHW + p];
  v.x = v.x * rsqrtf(pp[0] * inv + 1e-5f) * wc + bc;
  v.y = v.y * rsqrtf(pp[1] * inv + 1e-5f) * wc + bc;
  v.z = v.z * rsqrtf(pp[2] * inv + 1e-5f) * wc + bc;
  v.w = v.w * rsqrtf(pp[3] * inv + 1e-5f) * wc + bc;
  *(float4*)(y + i) = v;
}

extern "C" void kernel_launch(void* const* d_in, const int* in_sizes, int n_in,
                              void* d_out, int out_size, void* d_ws, size_t ws_size,
                              hipStream_t stream) {
  const float* x = (const float*)d_in[0];
  const float* wq = (const float*)d_in[1];
  const float* wk = (const float*)d_in[2];
  const float* wv = (const float*)d_in[3];
  const float* wdw = (const float*)d_in[4];
  const float* wpw = (const float*)d_in[5];
  const float* wout = (const float*)d_in[6];
  const float* rw = (const float*)d_in[7];
  const float* rb = (const float*)d_in[8];
  float* y = (float*)d_out;

  convert_weights<<<6480, 256, 0, stream>>>(wq, wk, wv, wout);
  transpose_x<<<dim3(128, 36, 2), dim3(32, 8), 0, stream>>>(x);
  gemm1_kernel<<<576, 512, 0, stream>>>();
  conv_kernel<<<dim3(2, 432, 2), 256, 0, stream>>>(wdw, wpw);
  attn_kernel<<<dim3(288, 2), 256, 0, stream>>>();
  rms_zero<<<32, 256, 0, stream>>>();
  gemm2_kernel<<<576, 256, 0, stream>>>(y);
  rms_norm<<<9216, 256, 0, stream>>>(y, rw, rb);
}

// Round 19
// 432.740 us; speedup vs baseline: 1.1003x; 1.0123x over previous
//
#include <hip/hip_runtime.h>

typedef _Float16 f16;
typedef f16 f16x8 __attribute__((ext_vector_type(8)));
typedef float f32x16 __attribute__((ext_vector_type(16)));

#define NB 2
#define NC 1152
#define NHW 4096
#define NCH3 3456
#define NC2 2304

#define LO_SCALE 2048.0f
#define LO_INV (1.0f / 2048.0f)

// ===== Channel permutation =====
// Permuted row p = role*1152 + g*8 + r  <->  original channel c = g*24 + role*8 + r
// q-role rows are p < 1152 -> contiguous; fp32-fidelity split applies there only.
// qkv, ms stored permuted and in f16.

__device__ __align__(16) f16 g_Wcat_h[(size_t)NCH3 * NC];
__device__ __align__(16) f16 g_Wcat_l[(size_t)NC * NC];
__device__ __align__(16) f16 g_WoutB_h[(size_t)NC * NC2];
__device__ __align__(16) f16 g_XT_h[(size_t)NB * NHW * NC];
__device__ __align__(16) f16 g_XT_l[(size_t)NB * NHW * NC];
__device__ __align__(16) f16 g_qkv[(size_t)NB * NCH3 * NHW];
__device__ __align__(16) f16 g_ms[(size_t)NB * NCH3 * NHW];
__device__ __align__(16) f16 g_attnT_h[(size_t)NB * NHW * NC2];
__device__ float g_part[NB * NHW];

__device__ __forceinline__ void gload16(const void* g, void* l) {
  __builtin_amdgcn_global_load_lds(
      (const __attribute__((address_space(1))) unsigned int*)g,
      (__attribute__((address_space(3))) unsigned int*)l, 16, 0, 0);
}

__device__ __forceinline__ void split_f16(float v, f16& h, f16& l) {
  h = (f16)v;
  l = (f16)((v - (float)h) * LO_SCALE);
}

// ---------- weight conversion (role-permuted rows) ----------
__global__ __launch_bounds__(256) void convert_weights(
    const float* __restrict__ wq, const float* __restrict__ wk,
    const float* __restrict__ wv, const float* __restrict__ wout) {
  size_t idx = ((size_t)blockIdx.x * 256 + threadIdx.x) * 4;
  const size_t NWC = (size_t)NCH3 * NC;
  const size_t NWO = (size_t)NC * NC2;
  if (idx < NWC) {
    int p = (int)(idx / NC);
    int kk = (int)(idx % NC);
    int role = p / 1152, w = p % 1152;
    int g = w >> 3, r = w & 7;
    int c = g * 24 + role * 8 + r;
    const float* src = (c < 1152) ? wq + (size_t)c * NC + kk
                      : (c < 2304) ? wk + (size_t)(c - 1152) * NC + kk
                                   : wv + (size_t)(c - 2304) * NC + kk;
    if (p < 1152) {
#pragma unroll
      for (int j = 0; j < 4; ++j)
        split_f16(src[j], g_Wcat_h[idx + j], g_Wcat_l[idx + j]);
    } else {
#pragma unroll
      for (int j = 0; j < 4; ++j) g_Wcat_h[idx + j] = (f16)src[j];
    }
  } else {
    size_t k = idx - NWC;
    if (k < NWO) {
      const float* src = wout + k;
#pragma unroll
      for (int j = 0; j < 4; ++j) g_WoutB_h[k + j] = (f16)src[j];
    }
  }
}

// ---------- x (B,C,HW) fp32 -> XT (B,HW,C) scaled-split f16 ----------
__global__ __launch_bounds__(256) void transpose_x(const float* __restrict__ x) {
  __shared__ float tile[32][33];
  int z = blockIdx.z;
  int p0 = blockIdx.x * 32, c0 = blockIdx.y * 32;
  int tx = threadIdx.x, ty = threadIdx.y;
#pragma unroll
  for (int i = 0; i < 32; i += 8)
    tile[ty + i][tx] = x[((size_t)z * NC + c0 + ty + i) * NHW + p0 + tx];
  __syncthreads();
#pragma unroll
  for (int i = 0; i < 32; i += 8) {
    size_t o = ((size_t)z * NHW + p0 + ty + i) * NC + c0 + tx;
    split_f16(tile[tx][ty + i], g_XT_h[o], g_XT_l[o]);
  }
}

// ===== gemm1 q-part (split-f16, fp32 fidelity): 128x256, deep 3-buf,
// one barrier per K-tile, counted vmcnt(6).
__device__ __forceinline__ void gemm1_split_deep(char* smem, int bm, int bn, int bz) {
  const int tid = threadIdx.x;
  const int lane = tid & 63;
  const int wid = tid >> 6;
  const int wr = wid >> 2, wc = wid & 3;
  const size_t boff = (size_t)bz * ((size_t)NHW * NC);
  const f16* Bh = g_XT_h + boff;
  const f16* Bl = g_XT_l + boff;
  f16* Cb = g_qkv + (size_t)bz * ((size_t)NCH3 * NHW);
  const int srow = tid >> 2;
  const int skb = (((tid & 3) ^ ((srow >> 1) & 3)) * 8);
  const f16* gAh = g_Wcat_h + (size_t)(bm + srow) * NC + skb;
  const f16* gAl = g_Wcat_l + (size_t)(bm + srow) * NC + skb;
  const f16* gBh0 = Bh + (size_t)(bn + srow) * NC + skb;
  const f16* gBl0 = Bl + (size_t)(bn + srow) * NC + skb;
  const f16* gBh1 = Bh + (size_t)(bn + 128 + srow) * NC + skb;
  const f16* gBl1 = Bl + (size_t)(bn + 128 + srow) * NC + skb;
  const int ldso = tid * 16;

  f32x16 acc[2][2] = {};
  f32x16 acc2[2][2] = {};
  const int r31 = lane & 31;
  const int key = (r31 >> 1) & 3;
  const int kblk = lane >> 5;

#define BUFS(b, off) (smem + (b) * 49152 + (off))
#define STG_S0(buf, tile)                                       \
  do {                                                          \
    size_t ko = (size_t)(tile) * 32;                            \
    gload16(gAh + ko, BUFS(buf, 0) + ldso);                     \
    gload16(gAl + ko, BUFS(buf, 8192) + ldso);                  \
    gload16(gBh0 + ko, BUFS(buf, 16384) + ldso);                \
  } while (0)
#define STG_S1(buf, tile)                                       \
  do {                                                          \
    size_t ko = (size_t)(tile) * 32;                            \
    gload16(gBh1 + ko, BUFS(buf, 24576) + ldso);                \
    gload16(gBl0 + ko, BUFS(buf, 32768) + ldso);                \
    gload16(gBl1 + ko, BUFS(buf, 40960) + ldso);                \
  } while (0)

#define FPH_S(buf, kh, STG)                                                    \
  do {                                                                         \
    STG;                                                                       \
    const int bsw = (((kh) * 2 + kblk) ^ key) * 8;                             \
    const f16* sAh = (const f16*)BUFS(buf, 0);                                 \
    const f16* sAl = (const f16*)BUFS(buf, 8192);                              \
    const f16* sBh = (const f16*)BUFS(buf, 16384);                             \
    const f16* sBl = (const f16*)BUFS(buf, 32768);                             \
    f16x8 ah[2], al[2], bh[2], bl[2];                                          \
    _Pragma("unroll") for (int mb = 0; mb < 2; ++mb) {                         \
      int ro = (wr * 64 + mb * 32 + r31) * 32 + bsw;                           \
      ah[mb] = *(const f16x8*)(sAh + ro);                                      \
      al[mb] = *(const f16x8*)(sAl + ro);                                      \
    }                                                                          \
    _Pragma("unroll") for (int nb = 0; nb < 2; ++nb) {                         \
      int ro = (wc * 64 + nb * 32 + r31) * 32 + bsw;                           \
      bh[nb] = *(const f16x8*)(sBh + ro);                                      \
      bl[nb] = *(const f16x8*)(sBl + ro);                                      \
    }                                                                          \
    __builtin_amdgcn_s_setprio(1);                                             \
    _Pragma("unroll") for (int mb = 0; mb < 2; ++mb)                           \
      _Pragma("unroll") for (int nb = 0; nb < 2; ++nb) {                       \
        acc[mb][nb]  = __builtin_amdgcn_mfma_f32_32x32x16_f16(ah[mb], bh[nb], acc[mb][nb], 0, 0, 0);  \
        acc2[mb][nb] = __builtin_amdgcn_mfma_f32_32x32x16_f16(ah[mb], bl[nb], acc2[mb][nb], 0, 0, 0); \
        acc2[mb][nb] = __builtin_amdgcn_mfma_f32_32x32x16_f16(al[mb], bh[nb], acc2[mb][nb], 0, 0, 0); \
      }                                                                        \
    __builtin_amdgcn_s_setprio(0);                                             \
  } while (0)

  const int NT = NC / 32;  // 36
  STG_S0(0, 0); STG_S1(0, 0);
  STG_S0(1, 1); STG_S1(1, 1);
  int cb = 0;
#pragma unroll 1
  for (int t = 0; t < NT - 2; ++t) {
    asm volatile("s_waitcnt vmcnt(6)" ::: "memory");
    __builtin_amdgcn_s_barrier();
    int pb = cb + 2; if (pb >= 3) pb -= 3;
    FPH_S(cb, 0, STG_S0(pb, t + 2));
    FPH_S(cb, 1, STG_S1(pb, t + 2));
    cb = (cb == 2) ? 0 : cb + 1;
  }
  asm volatile("s_waitcnt vmcnt(6)" ::: "memory");
  __builtin_amdgcn_s_barrier();
  FPH_S(cb, 0, (void)0);
  FPH_S(cb, 1, (void)0);
  cb = (cb == 2) ? 0 : cb + 1;
  asm volatile("s_waitcnt vmcnt(0)" ::: "memory");
  __builtin_amdgcn_s_barrier();
  FPH_S(cb, 0, (void)0);
  FPH_S(cb, 1, (void)0);
#undef STG_S0
#undef STG_S1
#undef FPH_S
#undef BUFS
#pragma unroll
  for (int mb = 0; mb < 2; ++mb)
#pragma unroll
    for (int nb = 0; nb < 2; ++nb) {
      int col = bn + wc * 64 + nb * 32 + r31;
#pragma unroll
      for (int reg = 0; reg < 16; ++reg) {
        int row = bm + wr * 64 + mb * 32 + (reg & 3) + 8 * (reg >> 2) + 4 * (lane >> 5);
        Cb[(size_t)row * NHW + col] = (f16)(acc[mb][nb][reg] + acc2[mb][nb][reg] * LO_INV);
      }
    }
}

// ===== gemm1 kv-part (plain f16): 128x256, deep 3-buf, 3 loads/tile, vmcnt(3)
__device__ __forceinline__ void gemm1_kv_deep(char* smem, int bmG, int bn, int bz) {
  f16* sA0 = (f16*)smem;                 // 3 x 8KB
  f16* sB0 = (f16*)(smem + 24576);       // 3 x 16KB
  const int tid = threadIdx.x;
  const int lane = tid & 63;
  const int wid = tid >> 6;
  const int wr = wid >> 2, wc = wid & 3;  // wave tile 64x64
  const f16* Bb = g_XT_h + (size_t)bz * ((size_t)NHW * NC);
  f16* Cb = g_qkv + (size_t)bz * ((size_t)NCH3 * NHW);
  const int srow = tid >> 2;
  const int skb = (((tid & 3) ^ ((srow >> 1) & 3)) * 8);
  const f16* gA0 = g_Wcat_h + (size_t)(bmG + srow) * NC + skb;
  const f16* gB0 = Bb + (size_t)(bn + srow) * NC + skb;
  const f16* gB1 = Bb + (size_t)(bn + 128 + srow) * NC + skb;
  const int ldso = tid * 16;

  f32x16 acc[2][2] = {};
  const int r31 = lane & 31;
  const int key = (r31 >> 1) & 3;
  const int kblk = lane >> 5;

#define SA(b) (sA0 + (b) * 4096)
#define SB(b) (sB0 + (b) * 8192)
#define STG_KV(buf, tile)                                       \
  do {                                                          \
    size_t ko = (size_t)(tile) * 32;                            \
    gload16(gA0 + ko, (char*)SA(buf) + ldso);                   \
    gload16(gB0 + ko, (char*)SB(buf) + ldso);                   \
    gload16(gB1 + ko, (char*)SB(buf) + 8192 + ldso);            \
  } while (0)
#define FPH_KV(buf, ks, STG)                                                   \
  do {                                                                         \
    STG;                                                                       \
    const int bsw = (((ks) * 2 + kblk) ^ key) * 8;                             \
    f16x8 af[2], bf[2];                                                        \
    _Pragma("unroll") for (int mb = 0; mb < 2; ++mb) {                         \
      int row = wr * 64 + mb * 32 + r31;                                       \
      af[mb] = *(const f16x8*)(SA(buf) + row * 32 + bsw);                      \
    }                                                                          \
    _Pragma("unroll") for (int nb = 0; nb < 2; ++nb) {                         \
      int row = wc * 64 + nb * 32 + r31;                                       \
      bf[nb] = *(const f16x8*)(SB(buf) + row * 32 + bsw);                      \
    }                                                                          \
    __builtin_amdgcn_s_setprio(1);                                             \
    _Pragma("unroll") for (int mb = 0; mb < 2; ++mb)                           \
      _Pragma("unroll") for (int nb = 0; nb < 2; ++nb)                         \
        acc[mb][nb] = __builtin_amdgcn_mfma_f32_32x32x16_f16(af[mb], bf[nb], acc[mb][nb], 0, 0, 0); \
    __builtin_amdgcn_s_setprio(0);                                             \
  } while (0)

  const int NT = NC / 32;  // 36
  STG_KV(0, 0);
  STG_KV(1, 1);
  int cb = 0;
#pragma unroll 1
  for (int t = 0; t < NT - 2; ++t) {
    asm volatile("s_waitcnt vmcnt(3)" ::: "memory");
    __builtin_amdgcn_s_barrier();
    int pb = cb + 2; if (pb >= 3) pb -= 3;
    FPH_KV(cb, 0, STG_KV(pb, t + 2));
    FPH_KV(cb, 1, (void)0);
    cb = (cb == 2) ? 0 : cb + 1;
  }
  asm volatile("s_waitcnt vmcnt(3)" ::: "memory");
  __builtin_amdgcn_s_barrier();
  FPH_KV(cb, 0, (void)0);
  FPH_KV(cb, 1, (void)0);
  cb = (cb == 2) ? 0 : cb + 1;
  asm volatile("s_waitcnt vmcnt(0)" ::: "memory");
  __builtin_amdgcn_s_barrier();
  FPH_KV(cb, 0, (void)0);
  FPH_KV(cb, 1, (void)0);
#undef STG_KV
#undef FPH_KV
#undef SA
#undef SB
#pragma unroll
  for (int mb = 0; mb < 2; ++mb)
#pragma unroll
    for (int nb = 0; nb < 2; ++nb) {
      int col = bn + wc * 64 + nb * 32 + r31;
#pragma unroll
      for (int reg = 0; reg < 16; ++reg) {
        int row = bmG + wr * 64 + mb * 32 + (reg & 3) + 8 * (reg >> 2) + 4 * (lane >> 5);
        Cb[(size_t)row * NHW + col] = (f16)acc[mb][nb][reg];
      }
    }
}

// 864 blocks, class-interleaved: bid%3==0 -> split (288), else kv (576).
// Consecutive same-class ids share the B panel (bn,bz) for partial L2 reuse.
__global__ __launch_bounds__(512, 1) void gemm1_kernel() {
  __shared__ __align__(16) char smem[147456];
  int bid = blockIdx.x;
  int cls = bid % 3;
  int base = bid / 3;
  if (cls == 0) {
    int bx = base % 9, rem = base / 9;
    gemm1_split_deep(smem, bx * 128, (rem & 15) * 256, rem >> 4);
  } else {
    int k = base * 2 + (cls - 1);       // 0..575
    int bx = k % 18, rem = k / 18;      // 18 row-tiles of 128 in kv range
    gemm1_kv_deep(smem, 1152 + bx * 128, (rem & 15) * 256, rem >> 4);
  }
}

// ---------- gemm2: plain f16 (128x128, 4 waves) 2-phase depth-3 (round-16 body)
// + fused RMS partial-sum epilogue ----------
template <int M, int N, int K>
__device__ __forceinline__ void gemm_body_plain(
    const f16* __restrict__ A, const f16* __restrict__ Bt,
    float* __restrict__ C, int bm, int bn, int bz) {
  __shared__ __align__(16) f16 sA[3][128 * 32];
  __shared__ __align__(16) f16 sB[3][128 * 32];
  const int tid = threadIdx.x;
  const int lane = tid & 63;
  const int wid = tid >> 6;
  const int wr = wid >> 1, wc = wid & 1;
  const f16* Bb = Bt + (size_t)bz * ((size_t)N * K);
  float* Cb = C + (size_t)bz * ((size_t)M * N);
  const int srow = tid >> 2;
  const int skb = (((tid & 3) ^ ((srow >> 1) & 3)) * 8);
  const f16* gA0 = A + (size_t)(bm + srow) * K + skb;
  const f16* gA1 = A + (size_t)(bm + 64 + srow) * K + skb;
  const f16* gB0 = Bb + (size_t)(bn + srow) * K + skb;
  const f16* gB1 = Bb + (size_t)(bn + 64 + srow) * K + skb;
  const int ldso = tid * 16;

  f32x16 acc[2][2] = {};
  const int r31 = lane & 31;
  const int key = (r31 >> 1) & 3;
  const int kblk = lane >> 5;

#define STAGE_P(buf, tile)                              \
  do {                                                  \
    size_t ko = (size_t)(tile) * 32;                    \
    gload16(gA0 + ko, (char*)sA[buf] + ldso);           \
    gload16(gA1 + ko, (char*)sA[buf] + 4096 + ldso);    \
    gload16(gB0 + ko, (char*)sB[buf] + ldso);           \
    gload16(gB1 + ko, (char*)sB[buf] + 4096 + ldso);    \
  } while (0)

#define COMPUTE_P(buf)                                                         \
  do {                                                                         \
    _Pragma("unroll") for (int kh = 0; kh < 2; ++kh) {                         \
      const int bsw = ((kh * 2 + kblk) ^ key) * 8;                             \
      f16x8 af[2], bf[2];                                                      \
      _Pragma("unroll") for (int mb = 0; mb < 2; ++mb)                         \
        af[mb] = *(const f16x8*)(sA[buf] + (wr * 64 + mb * 32 + r31) * 32 + bsw); \
      _Pragma("unroll") for (int nb = 0; nb < 2; ++nb)                         \
        bf[nb] = *(const f16x8*)(sB[buf] + (wc * 64 + nb * 32 + r31) * 32 + bsw); \
      __builtin_amdgcn_s_setprio(1);                                           \
      _Pragma("unroll") for (int mb = 0; mb < 2; ++mb)                         \
        _Pragma("unroll") for (int nb = 0; nb < 2; ++nb)                       \
          acc[mb][nb] = __builtin_amdgcn_mfma_f32_32x32x16_f16(af[mb], bf[nb], acc[mb][nb], 0, 0, 0); \
      __builtin_amdgcn_s_setprio(0);                                           \
    }                                                                          \
  } while (0)

  const int NT = K / 32;  // 72
  STAGE_P(0, 0);
  STAGE_P(1, 1);
  int cb = 0, sb = 2;
#pragma unroll 1
  for (int t = 0; t < NT - 1; ++t) {
    asm volatile("s_waitcnt vmcnt(4)" ::: "memory");
    __builtin_amdgcn_s_barrier();
    __builtin_amdgcn_sched_barrier(0);
    if (t + 2 < NT) STAGE_P(sb, t + 2);
    COMPUTE_P(cb);
    __builtin_amdgcn_sched_barrier(0);
    __builtin_amdgcn_s_barrier();
    cb = (cb == 2) ? 0 : cb + 1;
    sb = (sb == 2) ? 0 : sb + 1;
  }
  asm volatile("s_waitcnt vmcnt(0)" ::: "memory");
  __builtin_amdgcn_s_barrier();
  __builtin_amdgcn_sched_barrier(0);
  COMPUTE_P(cb);
#undef STAGE_P
#undef COMPUTE_P
#pragma unroll
  for (int nb = 0; nb < 2; ++nb) {
    int col = bn + wc * 64 + nb * 32 + r31;
    float csum = 0.f;
#pragma unroll
    for (int mb = 0; mb < 2; ++mb)
#pragma unroll
      for (int reg = 0; reg < 16; ++reg) {
        int row = bm + wr * 64 + mb * 32 + (reg & 3) + 8 * (reg >> 2) + 4 * (lane >> 5);
        float v = acc[mb][nb][reg];
        Cb[(size_t)row * N + col] = v;
        csum += v * v;
      }
    atomicAdd(&g_part[bz * NHW + col], csum);
  }
}

__global__ __launch_bounds__(256, 2) void gemm2_kernel(float* __restrict__ out) {
  int bid = blockIdx.x;
  int swz = (bid & 7) * (576 / 8) + (bid >> 3);
  int bx = swz % 9, rem = swz / 9;
  int by = rem & 31, bz = rem >> 5;
  gemm_body_plain<NC, NHW, NC2>(g_WoutB_h, g_attnT_h, out,
                                bx * 128, by * 128, bz);
}

// ---------- fused depthwise 5x5 + grouped 1x1 (f16 io, fp32 math, 8 px/thr) ----------
__global__ __launch_bounds__(256) void conv_kernel(const float* __restrict__ wdw,
                                                   const float* __restrict__ wpw) {
  const int z = blockIdx.z, gg = blockIdx.y;  // 0..431
  const int pbase = (gg % 3) * 1152 + (gg / 3) * 8;
  const int px = blockIdx.x * 2048 + threadIdx.x * 8;
  const int h = px >> 6, w0 = px & 63;
  const f16* base = g_qkv + ((size_t)z * NCH3 + pbase) * NHW;

  float dw[8][8];
#pragma unroll
  for (int ci = 0; ci < 8; ++ci) {
    const float* wd = wdw + (gg * 8 + ci) * 25;
    const f16* srcc = base + (size_t)ci * NHW;
    float acc[8] = {};
#pragma unroll
    for (int dy = -2; dy <= 2; ++dy) {
      int hh = h + dy;
      if (hh < 0 || hh > 63) continue;
      const f16* row = srcc + hh * 64;
      f16x8 Lv = {}, Rv = {};
      if (w0 >= 8) Lv = *(const f16x8*)(row + w0 - 8);
      f16x8 Mv = *(const f16x8*)(row + w0);
      if (w0 <= 48) Rv = *(const f16x8*)(row + w0 + 8);
      float c[24];
#pragma unroll
      for (int i = 0; i < 8; ++i) {
        c[i] = (float)Lv[i];
        c[8 + i] = (float)Mv[i];
        c[16 + i] = (float)Rv[i];
      }
      const float* wrow = wd + (dy + 2) * 5;
#pragma unroll
      for (int dx = 0; dx < 5; ++dx) {
        float wv = wrow[dx];
#pragma unroll
        for (int j = 0; j < 8; ++j) acc[j] += c[6 + j + dx] * wv;
      }
    }
#pragma unroll
    for (int j = 0; j < 8; ++j) dw[ci][j] = acc[j];
  }
#pragma unroll
  for (int o = 0; o < 8; ++o) {
    const float* wp = wpw + (size_t)(gg * 8 + o) * 8;
    float out[8] = {};
#pragma unroll
    for (int i = 0; i < 8; ++i) {
      float wv = wp[i];
#pragma unroll
      for (int j = 0; j < 8; ++j) out[j] += wv * dw[i][j];
    }
    f16x8 ov;
#pragma unroll
    for (int j = 0; j < 8; ++j) ov[j] = (f16)out[j];
    *(f16x8*)(g_ms + ((size_t)z * NCH3 + pbase + o) * NHW + px) = ov;
  }
}

// ---------- linear attention per (group, batch): f16 reads, 8 px/thread ----------
__global__ __launch_bounds__(256) void attn_kernel() {
  int g = blockIdx.x;
  int z = blockIdx.y;
  int tid = threadIdx.x;
  const f16* buf = (g < 144) ? g_qkv : g_ms;
  int gq = (g < 144) ? g : g - 144;
  const f16* qp = buf + ((size_t)z * NCH3 + gq * 8) * NHW;
  const f16* kp = buf + ((size_t)z * NCH3 + 1152 + gq * 8) * NHW;
  const f16* vp = buf + ((size_t)z * NCH3 + 2304 + gq * 8) * NHW;

  float s[9][8];
#pragma unroll
  for (int d = 0; d < 9; ++d)
#pragma unroll
    for (int e = 0; e < 8; ++e) s[d][e] = 0.f;

  for (int p0 = tid * 8; p0 < NHW; p0 += 2048) {
    f16x8 kx[8], vx[8];
#pragma unroll
    for (int e = 0; e < 8; ++e) kx[e] = *(const f16x8*)(kp + (size_t)e * NHW + p0);
#pragma unroll
    for (int d = 0; d < 8; ++d) vx[d] = *(const f16x8*)(vp + (size_t)d * NHW + p0);
#pragma unroll
    for (int j = 0; j < 8; ++j) {
      float kv[8], vv[8];
#pragma unroll
      for (int e = 0; e < 8; ++e) kv[e] = fmaxf((float)kx[e][j], 0.f);
#pragma unroll
      for (int d = 0; d < 8; ++d) vv[d] = (float)vx[d][j];
#pragma unroll
      for (int e = 0; e < 8; ++e) {
#pragma unroll
        for (int d = 0; d < 8; ++d) s[d][e] += vv[d] * kv[e];
        s[8][e] += kv[e];
      }
    }
  }
#pragma unroll
  for (int d = 0; d < 9; ++d)
#pragma unroll
    for (int e = 0; e < 8; ++e) {
      float v = s[d][e];
#pragma unroll
      for (int off = 32; off > 0; off >>= 1) v += __shfl_xor(v, off, 64);
      s[d][e] = v;
    }
  __shared__ float sred[4][72];
  __shared__ float sc[72];
  int w = tid >> 6, lane = tid & 63;
  if (lane == 0) {
#pragma unroll
    for (int d = 0; d < 9; ++d)
#pragma unroll
      for (int e = 0; e < 8; ++e) sred[w][d * 8 + e] = s[d][e];
  }
  __syncthreads();
  if (tid < 72) sc[tid] = sred[0][tid] + sred[1][tid] + sred[2][tid] + sred[3][tid];
  __syncthreads();
  float scl[9][8];
#pragma unroll
  for (int d = 0; d < 9; ++d)
#pragma unroll
    for (int e = 0; e < 8; ++e) scl[d][e] = sc[d * 8 + e];

  for (int p0 = tid * 8; p0 < NHW; p0 += 2048) {
    f16x8 qx[8];
#pragma unroll
    for (int e = 0; e < 8; ++e) qx[e] = *(const f16x8*)(qp + (size_t)e * NHW + p0);
#pragma unroll
    for (int j = 0; j < 8; ++j) {
      float qv[8];
#pragma unroll
      for (int e = 0; e < 8; ++e) qv[e] = fmaxf((float)qx[e][j], 0.f);
      float o[9];
#pragma unroll
      for (int d = 0; d < 9; ++d) {
        float a = 0.f;
#pragma unroll
        for (int e = 0; e < 8; ++e) a += scl[d][e] * qv[e];
        o[d] = a;
      }
      float r = 1.f / (o[8] + 1e-15f);
      f16x8 oh;
#pragma unroll
      for (int d = 0; d < 8; ++d) oh[d] = (f16)(o[d] * r);
      *(f16x8*)(g_attnT_h + ((size_t)z * NHW + p0 + j) * NC2 + g * 8) = oh;
    }
  }
}

// ---------- RMSNorm (partial sums fused into gemm2 epilogue) ----------
__global__ __launch_bounds__(256) void rms_zero() {
  g_part[blockIdx.x * 256 + threadIdx.x] = 0.f;
}
__global__ __launch_bounds__(256) void rms_norm(float* __restrict__ y,
                                                const float* __restrict__ w,
                                                const float* __restrict__ b) {
  size_t i = ((size_t)blockIdx.x * 256 + threadIdx.x) * 4;
  float4 v = *(const float4*)(y + i);
  int p = (int)(i & (NHW - 1));
  int c = (int)((i >> 12) % NC);
  int z = (int)(i / ((size_t)NC * NHW));
  const float inv = 1.0f / NC;
  float wc = w[c], bc = b[c];
  const float* pp = &g_part[z * NHW + p];
  v.x = v.x * rsqrtf(pp[0] * inv + 1e-5f) * wc + bc;
  v.y = v.y * rsqrtf(pp[1] * inv + 1e-5f) * wc + bc;
  v.z = v.z * rsqrtf(pp[2] * inv + 1e-5f) * wc + bc;
  v.w = v.w * rsqrtf(pp[3] * inv + 1e-5f) * wc + bc;
  *(float4*)(y + i) = v;
}

extern "C" void kernel_launch(void* const* d_in, const int* in_sizes, int n_in,
                              void* d_out, int out_size, void* d_ws, size_t ws_size,
                              hipStream_t stream) {
  const float* x = (const float*)d_in[0];
  const float* wq = (const float*)d_in[1];
  const float* wk = (const float*)d_in[2];
  const float* wv = (const float*)d_in[3];
  const float* wdw = (const float*)d_in[4];
  const float* wpw = (const float*)d_in[5];
  const float* wout = (const float*)d_in[6];
  const float* rw = (const float*)d_in[7];
  const float* rb = (const float*)d_in[8];
  float* y = (float*)d_out;

  convert_weights<<<6480, 256, 0, stream>>>(wq, wk, wv, wout);
  transpose_x<<<dim3(128, 36, 2), dim3(32, 8), 0, stream>>>(x);
  gemm1_kernel<<<864, 512, 0, stream>>>();
  conv_kernel<<<dim3(2, 432, 2), 256, 0, stream>>>(wdw, wpw);
  attn_kernel<<<dim3(288, 2), 256, 0, stream>>>();
  rms_zero<<<32, 256, 0, stream>>>();
  gemm2_kernel<<<576, 256, 0, stream>>>(y);
  rms_norm<<<9216, 256, 0, stream>>>(y, rw, rb);
}

// Round 20
// 431.892 us; speedup vs baseline: 1.1024x; 1.0020x over previous
//
#include <hip/hip_runtime.h>

typedef _Float16 f16;
typedef f16 f16x8 __attribute__((ext_vector_type(8)));
typedef float f32x16 __attribute__((ext_vector_type(16)));

#define NB 2
#define NC 1152
#define NHW 4096
#define NCH3 3456
#define NC2 2304

#define LO_SCALE 2048.0f
#define LO_INV (1.0f / 2048.0f)

// ===== Channel permutation =====
// Permuted row p = role*1152 + g*8 + r  <->  original channel c = g*24 + role*8 + r
// q-role rows are p < 1152 -> contiguous; fp32-fidelity split applies there only.
// qkv, ms stored permuted and in f16.

__device__ __align__(16) f16 g_Wcat_h[(size_t)NCH3 * NC];
__device__ __align__(16) f16 g_Wcat_l[(size_t)NC * NC];
__device__ __align__(16) f16 g_WoutB_h[(size_t)NC * NC2];
__device__ __align__(16) f16 g_XT_h[(size_t)NB * NHW * NC];
__device__ __align__(16) f16 g_XT_l[(size_t)NB * NHW * NC];
__device__ __align__(16) f16 g_qkv[(size_t)NB * NCH3 * NHW];
__device__ __align__(16) f16 g_ms[(size_t)NB * NCH3 * NHW];
__device__ __align__(16) f16 g_attnT_h[(size_t)NB * NHW * NC2];
__device__ float g_part[NB * NHW];

__device__ __forceinline__ void gload16(const void* g, void* l) {
  __builtin_amdgcn_global_load_lds(
      (const __attribute__((address_space(1))) unsigned int*)g,
      (__attribute__((address_space(3))) unsigned int*)l, 16, 0, 0);
}

__device__ __forceinline__ void split_f16(float v, f16& h, f16& l) {
  h = (f16)v;
  l = (f16)((v - (float)h) * LO_SCALE);
}

// ---------- weight conversion (role-permuted rows) ----------
__global__ __launch_bounds__(256) void convert_weights(
    const float* __restrict__ wq, const float* __restrict__ wk,
    const float* __restrict__ wv, const float* __restrict__ wout) {
  size_t idx = ((size_t)blockIdx.x * 256 + threadIdx.x) * 4;
  const size_t NWC = (size_t)NCH3 * NC;
  const size_t NWO = (size_t)NC * NC2;
  if (idx < NWC) {
    int p = (int)(idx / NC);
    int kk = (int)(idx % NC);
    int role = p / 1152, w = p % 1152;
    int g = w >> 3, r = w & 7;
    int c = g * 24 + role * 8 + r;
    const float* src = (c < 1152) ? wq + (size_t)c * NC + kk
                      : (c < 2304) ? wk + (size_t)(c - 1152) * NC + kk
                                   : wv + (size_t)(c - 2304) * NC + kk;
    if (p < 1152) {
#pragma unroll
      for (int j = 0; j < 4; ++j)
        split_f16(src[j], g_Wcat_h[idx + j], g_Wcat_l[idx + j]);
    } else {
#pragma unroll
      for (int j = 0; j < 4; ++j) g_Wcat_h[idx + j] = (f16)src[j];
    }
  } else {
    size_t k = idx - NWC;
    if (k < NWO) {
      const float* src = wout + k;
#pragma unroll
      for (int j = 0; j < 4; ++j) g_WoutB_h[k + j] = (f16)src[j];
    }
  }
}

// ---------- x (B,C,HW) fp32 -> XT (B,HW,C) scaled-split f16 ----------
__global__ __launch_bounds__(256) void transpose_x(const float* __restrict__ x) {
  __shared__ float tile[32][33];
  int z = blockIdx.z;
  int p0 = blockIdx.x * 32, c0 = blockIdx.y * 32;
  int tx = threadIdx.x, ty = threadIdx.y;
#pragma unroll
  for (int i = 0; i < 32; i += 8)
    tile[ty + i][tx] = x[((size_t)z * NC + c0 + ty + i) * NHW + p0 + tx];
  __syncthreads();
#pragma unroll
  for (int i = 0; i < 32; i += 8) {
    size_t o = ((size_t)z * NHW + p0 + ty + i) * NC + c0 + tx;
    split_f16(tile[tx][ty + i], g_XT_h[o], g_XT_l[o]);
  }
}

// ===== gemm1 q-part (split-f16, fp32 fidelity): 128x256, deep 3-buf,
// one barrier per K-tile, counted vmcnt(6).
__device__ __forceinline__ void gemm1_split_deep(char* smem, int bm, int bn, int bz) {
  const int tid = threadIdx.x;
  const int lane = tid & 63;
  const int wid = tid >> 6;
  const int wr = wid >> 2, wc = wid & 3;
  const size_t boff = (size_t)bz * ((size_t)NHW * NC);
  const f16* Bh = g_XT_h + boff;
  const f16* Bl = g_XT_l + boff;
  f16* Cb = g_qkv + (size_t)bz * ((size_t)NCH3 * NHW);
  const int srow = tid >> 2;
  const int skb = (((tid & 3) ^ ((srow >> 1) & 3)) * 8);
  const f16* gAh = g_Wcat_h + (size_t)(bm + srow) * NC + skb;
  const f16* gAl = g_Wcat_l + (size_t)(bm + srow) * NC + skb;
  const f16* gBh0 = Bh + (size_t)(bn + srow) * NC + skb;
  const f16* gBl0 = Bl + (size_t)(bn + srow) * NC + skb;
  const f16* gBh1 = Bh + (size_t)(bn + 128 + srow) * NC + skb;
  const f16* gBl1 = Bl + (size_t)(bn + 128 + srow) * NC + skb;
  const int ldso = tid * 16;

  f32x16 acc[2][2] = {};
  f32x16 acc2[2][2] = {};
  const int r31 = lane & 31;
  const int key = (r31 >> 1) & 3;
  const int kblk = lane >> 5;

#define BUFS(b, off) (smem + (b) * 49152 + (off))
#define STG_S0(buf, tile)                                       \
  do {                                                          \
    size_t ko = (size_t)(tile) * 32;                            \
    gload16(gAh + ko, BUFS(buf, 0) + ldso);                     \
    gload16(gAl + ko, BUFS(buf, 8192) + ldso);                  \
    gload16(gBh0 + ko, BUFS(buf, 16384) + ldso);                \
  } while (0)
#define STG_S1(buf, tile)                                       \
  do {                                                          \
    size_t ko = (size_t)(tile) * 32;                            \
    gload16(gBh1 + ko, BUFS(buf, 24576) + ldso);                \
    gload16(gBl0 + ko, BUFS(buf, 32768) + ldso);                \
    gload16(gBl1 + ko, BUFS(buf, 40960) + ldso);                \
  } while (0)

#define FPH_S(buf, kh, STG)                                                    \
  do {                                                                         \
    STG;                                                                       \
    const int bsw = (((kh) * 2 + kblk) ^ key) * 8;                             \
    const f16* sAh = (const f16*)BUFS(buf, 0);                                 \
    const f16* sAl = (const f16*)BUFS(buf, 8192);                              \
    const f16* sBh = (const f16*)BUFS(buf, 16384);                             \
    const f16* sBl = (const f16*)BUFS(buf, 32768);                             \
    f16x8 ah[2], al[2], bh[2], bl[2];                                          \
    _Pragma("unroll") for (int mb = 0; mb < 2; ++mb) {                         \
      int ro = (wr * 64 + mb * 32 + r31) * 32 + bsw;                           \
      ah[mb] = *(const f16x8*)(sAh + ro);                                      \
      al[mb] = *(const f16x8*)(sAl + ro);                                      \
    }                                                                          \
    _Pragma("unroll") for (int nb = 0; nb < 2; ++nb) {                         \
      int ro = (wc * 64 + nb * 32 + r31) * 32 + bsw;                           \
      bh[nb] = *(const f16x8*)(sBh + ro);                                      \
      bl[nb] = *(const f16x8*)(sBl + ro);                                      \
    }                                                                          \
    __builtin_amdgcn_s_setprio(1);                                             \
    _Pragma("unroll") for (int mb = 0; mb < 2; ++mb)                           \
      _Pragma("unroll") for (int nb = 0; nb < 2; ++nb) {                       \
        acc[mb][nb]  = __builtin_amdgcn_mfma_f32_32x32x16_f16(ah[mb], bh[nb], acc[mb][nb], 0, 0, 0);  \
        acc2[mb][nb] = __builtin_amdgcn_mfma_f32_32x32x16_f16(ah[mb], bl[nb], acc2[mb][nb], 0, 0, 0); \
        acc2[mb][nb] = __builtin_amdgcn_mfma_f32_32x32x16_f16(al[mb], bh[nb], acc2[mb][nb], 0, 0, 0); \
      }                                                                        \
    __builtin_amdgcn_s_setprio(0);                                             \
  } while (0)

  const int NT = NC / 32;  // 36
  STG_S0(0, 0); STG_S1(0, 0);
  STG_S0(1, 1); STG_S1(1, 1);
  int cb = 0;
#pragma unroll 1
  for (int t = 0; t < NT - 2; ++t) {
    asm volatile("s_waitcnt vmcnt(6)" ::: "memory");
    __builtin_amdgcn_s_barrier();
    int pb = cb + 2; if (pb >= 3) pb -= 3;
    FPH_S(cb, 0, STG_S0(pb, t + 2));
    FPH_S(cb, 1, STG_S1(pb, t + 2));
    cb = (cb == 2) ? 0 : cb + 1;
  }
  asm volatile("s_waitcnt vmcnt(6)" ::: "memory");
  __builtin_amdgcn_s_barrier();
  FPH_S(cb, 0, (void)0);
  FPH_S(cb, 1, (void)0);
  cb = (cb == 2) ? 0 : cb + 1;
  asm volatile("s_waitcnt vmcnt(0)" ::: "memory");
  __builtin_amdgcn_s_barrier();
  FPH_S(cb, 0, (void)0);
  FPH_S(cb, 1, (void)0);
#undef STG_S0
#undef STG_S1
#undef FPH_S
#undef BUFS
#pragma unroll
  for (int mb = 0; mb < 2; ++mb)
#pragma unroll
    for (int nb = 0; nb < 2; ++nb) {
      int col = bn + wc * 64 + nb * 32 + r31;
#pragma unroll
      for (int reg = 0; reg < 16; ++reg) {
        int row = bm + wr * 64 + mb * 32 + (reg & 3) + 8 * (reg >> 2) + 4 * (lane >> 5);
        Cb[(size_t)row * NHW + col] = (f16)(acc[mb][nb][reg] + acc2[mb][nb][reg] * LO_INV);
      }
    }
}

// ===== gemm1 kv-part (plain f16): 128x256, deep 3-buf, 3 loads/tile, vmcnt(3)
__device__ __forceinline__ void gemm1_kv_deep(char* smem, int bmG, int bn, int bz) {
  f16* sA0 = (f16*)smem;                 // 3 x 8KB
  f16* sB0 = (f16*)(smem + 24576);       // 3 x 16KB
  const int tid = threadIdx.x;
  const int lane = tid & 63;
  const int wid = tid >> 6;
  const int wr = wid >> 2, wc = wid & 3;  // wave tile 64x64
  const f16* Bb = g_XT_h + (size_t)bz * ((size_t)NHW * NC);
  f16* Cb = g_qkv + (size_t)bz * ((size_t)NCH3 * NHW);
  const int srow = tid >> 2;
  const int skb = (((tid & 3) ^ ((srow >> 1) & 3)) * 8);
  const f16* gA0 = g_Wcat_h + (size_t)(bmG + srow) * NC + skb;
  const f16* gB0 = Bb + (size_t)(bn + srow) * NC + skb;
  const f16* gB1 = Bb + (size_t)(bn + 128 + srow) * NC + skb;
  const int ldso = tid * 16;

  f32x16 acc[2][2] = {};
  const int r31 = lane & 31;
  const int key = (r31 >> 1) & 3;
  const int kblk = lane >> 5;

#define SA(b) (sA0 + (b) * 4096)
#define SB(b) (sB0 + (b) * 8192)
#define STG_KV(buf, tile)                                       \
  do {                                                          \
    size_t ko = (size_t)(tile) * 32;                            \
    gload16(gA0 + ko, (char*)SA(buf) + ldso);                   \
    gload16(gB0 + ko, (char*)SB(buf) + ldso);                   \
    gload16(gB1 + ko, (char*)SB(buf) + 8192 + ldso);            \
  } while (0)
#define FPH_KV(buf, ks, STG)                                                   \
  do {                                                                         \
    STG;                                                                       \
    const int bsw = (((ks) * 2 + kblk) ^ key) * 8;                             \
    f16x8 af[2], bf[2];                                                        \
    _Pragma("unroll") for (int mb = 0; mb < 2; ++mb) {                         \
      int row = wr * 64 + mb * 32 + r31;                                       \
      af[mb] = *(const f16x8*)(SA(buf) + row * 32 + bsw);                      \
    }                                                                          \
    _Pragma("unroll") for (int nb = 0; nb < 2; ++nb) {                         \
      int row = wc * 64 + nb * 32 + r31;                                       \
      bf[nb] = *(const f16x8*)(SB(buf) + row * 32 + bsw);                      \
    }                                                                          \
    __builtin_amdgcn_s_setprio(1);                                             \
    _Pragma("unroll") for (int mb = 0; mb < 2; ++mb)                           \
      _Pragma("unroll") for (int nb = 0; nb < 2; ++nb)                         \
        acc[mb][nb] = __builtin_amdgcn_mfma_f32_32x32x16_f16(af[mb], bf[nb], acc[mb][nb], 0, 0, 0); \
    __builtin_amdgcn_s_setprio(0);                                             \
  } while (0)

  const int NT = NC / 32;  // 36
  STG_KV(0, 0);
  STG_KV(1, 1);
  int cb = 0;
#pragma unroll 1
  for (int t = 0; t < NT - 2; ++t) {
    asm volatile("s_waitcnt vmcnt(3)" ::: "memory");
    __builtin_amdgcn_s_barrier();
    int pb = cb + 2; if (pb >= 3) pb -= 3;
    FPH_KV(cb, 0, STG_KV(pb, t + 2));
    FPH_KV(cb, 1, (void)0);
    cb = (cb == 2) ? 0 : cb + 1;
  }
  asm volatile("s_waitcnt vmcnt(3)" ::: "memory");
  __builtin_amdgcn_s_barrier();
  FPH_KV(cb, 0, (void)0);
  FPH_KV(cb, 1, (void)0);
  cb = (cb == 2) ? 0 : cb + 1;
  asm volatile("s_waitcnt vmcnt(0)" ::: "memory");
  __builtin_amdgcn_s_barrier();
  FPH_KV(cb, 0, (void)0);
  FPH_KV(cb, 1, (void)0);
#undef STG_KV
#undef FPH_KV
#undef SA
#undef SB
#pragma unroll
  for (int mb = 0; mb < 2; ++mb)
#pragma unroll
    for (int nb = 0; nb < 2; ++nb) {
      int col = bn + wc * 64 + nb * 32 + r31;
#pragma unroll
      for (int reg = 0; reg < 16; ++reg) {
        int row = bmG + wr * 64 + mb * 32 + (reg & 3) + 8 * (reg >> 2) + 4 * (lane >> 5);
        Cb[(size_t)row * NHW + col] = (f16)acc[mb][nb][reg];
      }
    }
}

// 864 blocks = 32 B-panels x 27 blocks. Consecutive bids share the same
// B-panel (bn,bz) -> L2 reuse; each panel window mixes 9 long (split) +
// 18 short (kv) blocks -> temporal balance across CUs.
__global__ __launch_bounds__(512, 1) void gemm1_kernel() {
  __shared__ __align__(16) char smem[147456];
  int bid = blockIdx.x;
  int panel = bid / 27;        // 0..31
  int idx = bid % 27;          // 0..26
  int bn = (panel & 15) * 256;
  int bz = panel >> 4;
  if (idx < 9)
    gemm1_split_deep(smem, idx * 128, bn, bz);
  else
    gemm1_kv_deep(smem, 1152 + (idx - 9) * 128, bn, bz);
}

// ---------- gemm2: plain f16 (128x128, 4 waves) 2-phase depth-3 (round-16 body)
// + fused RMS partial-sum epilogue ----------
template <int M, int N, int K>
__device__ __forceinline__ void gemm_body_plain(
    const f16* __restrict__ A, const f16* __restrict__ Bt,
    float* __restrict__ C, int bm, int bn, int bz) {
  __shared__ __align__(16) f16 sA[3][128 * 32];
  __shared__ __align__(16) f16 sB[3][128 * 32];
  const int tid = threadIdx.x;
  const int lane = tid & 63;
  const int wid = tid >> 6;
  const int wr = wid >> 1, wc = wid & 1;
  const f16* Bb = Bt + (size_t)bz * ((size_t)N * K);
  float* Cb = C + (size_t)bz * ((size_t)M * N);
  const int srow = tid >> 2;
  const int skb = (((tid & 3) ^ ((srow >> 1) & 3)) * 8);
  const f16* gA0 = A + (size_t)(bm + srow) * K + skb;
  const f16* gA1 = A + (size_t)(bm + 64 + srow) * K + skb;
  const f16* gB0 = Bb + (size_t)(bn + srow) * K + skb;
  const f16* gB1 = Bb + (size_t)(bn + 64 + srow) * K + skb;
  const int ldso = tid * 16;

  f32x16 acc[2][2] = {};
  const int r31 = lane & 31;
  const int key = (r31 >> 1) & 3;
  const int kblk = lane >> 5;

#define STAGE_P(buf, tile)                              \
  do {                                                  \
    size_t ko = (size_t)(tile) * 32;                    \
    gload16(gA0 + ko, (char*)sA[buf] + ldso);           \
    gload16(gA1 + ko, (char*)sA[buf] + 4096 + ldso);    \
    gload16(gB0 + ko, (char*)sB[buf] + ldso);           \
    gload16(gB1 + ko, (char*)sB[buf] + 4096 + ldso);    \
  } while (0)

#define COMPUTE_P(buf)                                                         \
  do {                                                                         \
    _Pragma("unroll") for (int kh = 0; kh < 2; ++kh) {                         \
      const int bsw = ((kh * 2 + kblk) ^ key) * 8;                             \
      f16x8 af[2], bf[2];                                                      \
      _Pragma("unroll") for (int mb = 0; mb < 2; ++mb)                         \
        af[mb] = *(const f16x8*)(sA[buf] + (wr * 64 + mb * 32 + r31) * 32 + bsw); \
      _Pragma("unroll") for (int nb = 0; nb < 2; ++nb)                         \
        bf[nb] = *(const f16x8*)(sB[buf] + (wc * 64 + nb * 32 + r31) * 32 + bsw); \
      __builtin_amdgcn_s_setprio(1);                                           \
      _Pragma("unroll") for (int mb = 0; mb < 2; ++mb)                         \
        _Pragma("unroll") for (int nb = 0; nb < 2; ++nb)                       \
          acc[mb][nb] = __builtin_amdgcn_mfma_f32_32x32x16_f16(af[mb], bf[nb], acc[mb][nb], 0, 0, 0); \
      __builtin_amdgcn_s_setprio(0);                                           \
    }                                                                          \
  } while (0)

  const int NT = K / 32;  // 72
  STAGE_P(0, 0);
  STAGE_P(1, 1);
  int cb = 0, sb = 2;
#pragma unroll 1
  for (int t = 0; t < NT - 1; ++t) {
    asm volatile("s_waitcnt vmcnt(4)" ::: "memory");
    __builtin_amdgcn_s_barrier();
    __builtin_amdgcn_sched_barrier(0);
    if (t + 2 < NT) STAGE_P(sb, t + 2);
    COMPUTE_P(cb);
    __builtin_amdgcn_sched_barrier(0);
    __builtin_amdgcn_s_barrier();
    cb = (cb == 2) ? 0 : cb + 1;
    sb = (sb == 2) ? 0 : sb + 1;
  }
  asm volatile("s_waitcnt vmcnt(0)" ::: "memory");
  __builtin_amdgcn_s_barrier();
  __builtin_amdgcn_sched_barrier(0);
  COMPUTE_P(cb);
#undef STAGE_P
#undef COMPUTE_P
#pragma unroll
  for (int nb = 0; nb < 2; ++nb) {
    int col = bn + wc * 64 + nb * 32 + r31;
    float csum = 0.f;
#pragma unroll
    for (int mb = 0; mb < 2; ++mb)
#pragma unroll
      for (int reg = 0; reg < 16; ++reg) {
        int row = bm + wr * 64 + mb * 32 + (reg & 3) + 8 * (reg >> 2) + 4 * (lane >> 5);
        float v = acc[mb][nb][reg];
        Cb[(size_t)row * N + col] = v;
        csum += v * v;
      }
    atomicAdd(&g_part[bz * NHW + col], csum);
  }
}

__global__ __launch_bounds__(256, 2) void gemm2_kernel(float* __restrict__ out) {
  int bid = blockIdx.x;
  int swz = (bid & 7) * (576 / 8) + (bid >> 3);
  int bx = swz % 9, rem = swz / 9;
  int by = rem & 31, bz = rem >> 5;
  gemm_body_plain<NC, NHW, NC2>(g_WoutB_h, g_attnT_h, out,
                                bx * 128, by * 128, bz);
}

// ---------- fused depthwise 5x5 + grouped 1x1 (f16 io, fp32 math, 8 px/thr) ----------
__global__ __launch_bounds__(256) void conv_kernel(const float* __restrict__ wdw,
                                                   const float* __restrict__ wpw) {
  const int z = blockIdx.z, gg = blockIdx.y;  // 0..431
  const int pbase = (gg % 3) * 1152 + (gg / 3) * 8;
  const int px = blockIdx.x * 2048 + threadIdx.x * 8;
  const int h = px >> 6, w0 = px & 63;
  const f16* base = g_qkv + ((size_t)z * NCH3 + pbase) * NHW;

  float dw[8][8];
#pragma unroll
  for (int ci = 0; ci < 8; ++ci) {
    const float* wd = wdw + (gg * 8 + ci) * 25;
    const f16* srcc = base + (size_t)ci * NHW;
    float acc[8] = {};
#pragma unroll
    for (int dy = -2; dy <= 2; ++dy) {
      int hh = h + dy;
      if (hh < 0 || hh > 63) continue;
      const f16* row = srcc + hh * 64;
      f16x8 Lv = {}, Rv = {};
      if (w0 >= 8) Lv = *(const f16x8*)(row + w0 - 8);
      f16x8 Mv = *(const f16x8*)(row + w0);
      if (w0 <= 48) Rv = *(const f16x8*)(row + w0 + 8);
      float c[24];
#pragma unroll
      for (int i = 0; i < 8; ++i) {
        c[i] = (float)Lv[i];
        c[8 + i] = (float)Mv[i];
        c[16 + i] = (float)Rv[i];
      }
      const float* wrow = wd + (dy + 2) * 5;
#pragma unroll
      for (int dx = 0; dx < 5; ++dx) {
        float wv = wrow[dx];
#pragma unroll
        for (int j = 0; j < 8; ++j) acc[j] += c[6 + j + dx] * wv;
      }
    }
#pragma unroll
    for (int j = 0; j < 8; ++j) dw[ci][j] = acc[j];
  }
#pragma unroll
  for (int o = 0; o < 8; ++o) {
    const float* wp = wpw + (size_t)(gg * 8 + o) * 8;
    float out[8] = {};
#pragma unroll
    for (int i = 0; i < 8; ++i) {
      float wv = wp[i];
#pragma unroll
      for (int j = 0; j < 8; ++j) out[j] += wv * dw[i][j];
    }
    f16x8 ov;
#pragma unroll
    for (int j = 0; j < 8; ++j) ov[j] = (f16)out[j];
    *(f16x8*)(g_ms + ((size_t)z * NCH3 + pbase + o) * NHW + px) = ov;
  }
}

// ---------- linear attention per (group, batch): f16 reads, 8 px/thread ----------
__global__ __launch_bounds__(256) void attn_kernel() {
  int g = blockIdx.x;
  int z = blockIdx.y;
  int tid = threadIdx.x;
  const f16* buf = (g < 144) ? g_qkv : g_ms;
  int gq = (g < 144) ? g : g - 144;
  const f16* qp = buf + ((size_t)z * NCH3 + gq * 8) * NHW;
  const f16* kp = buf + ((size_t)z * NCH3 + 1152 + gq * 8) * NHW;
  const f16* vp = buf + ((size_t)z * NCH3 + 2304 + gq * 8) * NHW;

  float s[9][8];
#pragma unroll
  for (int d = 0; d < 9; ++d)
#pragma unroll
    for (int e = 0; e < 8; ++e) s[d][e] = 0.f;

  for (int p0 = tid * 8; p0 < NHW; p0 += 2048) {
    f16x8 kx[8], vx[8];
#pragma unroll
    for (int e = 0; e < 8; ++e) kx[e] = *(const f16x8*)(kp + (size_t)e * NHW + p0);
#pragma unroll
    for (int d = 0; d < 8; ++d) vx[d] = *(const f16x8*)(vp + (size_t)d * NHW + p0);
#pragma unroll
    for (int j = 0; j < 8; ++j) {
      float kv[8], vv[8];
#pragma unroll
      for (int e = 0; e < 8; ++e) kv[e] = fmaxf((float)kx[e][j], 0.f);
#pragma unroll
      for (int d = 0; d < 8; ++d) vv[d] = (float)vx[d][j];
#pragma unroll
      for (int e = 0; e < 8; ++e) {
#pragma unroll
        for (int d = 0; d < 8; ++d) s[d][e] += vv[d] * kv[e];
        s[8][e] += kv[e];
      }
    }
  }
#pragma unroll
  for (int d = 0; d < 9; ++d)
#pragma unroll
    for (int e = 0; e < 8; ++e) {
      float v = s[d][e];
#pragma unroll
      for (int off = 32; off > 0; off >>= 1) v += __shfl_xor(v, off, 64);
      s[d][e] = v;
    }
  __shared__ float sred[4][72];
  __shared__ float sc[72];
  int w = tid >> 6, lane = tid & 63;
  if (lane == 0) {
#pragma unroll
    for (int d = 0; d < 9; ++d)
#pragma unroll
      for (int e = 0; e < 8; ++e) sred[w][d * 8 + e] = s[d][e];
  }
  __syncthreads();
  if (tid < 72) sc[tid] = sred[0][tid] + sred[1][tid] + sred[2][tid] + sred[3][tid];
  __syncthreads();
  float scl[9][8];
#pragma unroll
  for (int d = 0; d < 9; ++d)
#pragma unroll
    for (int e = 0; e < 8; ++e) scl[d][e] = sc[d * 8 + e];

  for (int p0 = tid * 8; p0 < NHW; p0 += 2048) {
    f16x8 qx[8];
#pragma unroll
    for (int e = 0; e < 8; ++e) qx[e] = *(const f16x8*)(qp + (size_t)e * NHW + p0);
#pragma unroll
    for (int j = 0; j < 8; ++j) {
      float qv[8];
#pragma unroll
      for (int e = 0; e < 8; ++e) qv[e] = fmaxf((float)qx[e][j], 0.f);
      float o[9];
#pragma unroll
      for (int d = 0; d < 9; ++d) {
        float a = 0.f;
#pragma unroll
        for (int e = 0; e < 8; ++e) a += scl[d][e] * qv[e];
        o[d] = a;
      }
      float r = 1.f / (o[8] + 1e-15f);
      f16x8 oh;
#pragma unroll
      for (int d = 0; d < 8; ++d) oh[d] = (f16)(o[d] * r);
      *(f16x8*)(g_attnT_h + ((size_t)z * NHW + p0 + j) * NC2 + g * 8) = oh;
    }
  }
}

// ---------- RMSNorm (partial sums fused into gemm2 epilogue) ----------
__global__ __launch_bounds__(256) void rms_zero() {
  g_part[blockIdx.x * 256 + threadIdx.x] = 0.f;
}
__global__ __launch_bounds__(256) void rms_norm(float* __restrict__ y,
                                                const float* __restrict__ w,
                                                const float* __restrict__ b) {
  size_t i = ((size_t)blockIdx.x * 256 + threadIdx.x) * 4;
  float4 v = *(const float4*)(y + i);
  int p = (int)(i & (NHW - 1));
  int c = (int)((i >> 12) % NC);
  int z = (int)(i / ((size_t)NC * NHW));
  const float inv = 1.0f / NC;
  float wc = w[c], bc = b[c];
  const float* pp = &g_part[z * NHW + p];
  v.x = v.x * rsqrtf(pp[0] * inv + 1e-5f) * wc + bc;
  v.y = v.y * rsqrtf(pp[1] * inv + 1e-5f) * wc + bc;
  v.z = v.z * rsqrtf(pp[2] * inv + 1e-5f) * wc + bc;
  v.w = v.w * rsqrtf(pp[3] * inv + 1e-5f) * wc + bc;
  *(float4*)(y + i) = v;
}

extern "C" void kernel_launch(void* const* d_in, const int* in_sizes, int n_in,
                              void* d_out, int out_size, void* d_ws, size_t ws_size,
                              hipStream_t stream) {
  const float* x = (const float*)d_in[0];
  const float* wq = (const float*)d_in[1];
  const float* wk = (const float*)d_in[2];
  const float* wv = (const float*)d_in[3];
  const float* wdw = (const float*)d_in[4];
  const float* wpw = (const float*)d_in[5];
  const float* wout = (const float*)d_in[6];
  const float* rw = (const float*)d_in[7];
  const float* rb = (const float*)d_in[8];
  float* y = (float*)d_out;

  convert_weights<<<6480, 256, 0, stream>>>(wq, wk, wv, wout);
  transpose_x<<<dim3(128, 36, 2), dim3(32, 8), 0, stream>>>(x);
  gemm1_kernel<<<864, 512, 0, stream>>>();
  conv_kernel<<<dim3(2, 432, 2), 256, 0, stream>>>(wdw, wpw);
  attn_kernel<<<dim3(288, 2), 256, 0, stream>>>();
  rms_zero<<<32, 256, 0, stream>>>();
  gemm2_kernel<<<576, 256, 0, stream>>>(y);
  rms_norm<<<9216, 256, 0, stream>>>(y, rw, rb);
}

// Round 21
// 395.597 us; speedup vs baseline: 1.2036x; 1.0917x over previous
//
#include <hip/hip_runtime.h>

typedef _Float16 f16;
typedef f16 f16x8 __attribute__((ext_vector_type(8)));
typedef float f32x16 __attribute__((ext_vector_type(16)));

#define NB 2
#define NC 1152
#define NHW 4096
#define NCH3 3456
#define NC2 2304

#define LO_SCALE 2048.0f
#define LO_INV (1.0f / 2048.0f)

// ===== Channel permutation =====
// Permuted row p = role*1152 + g*8 + r  <->  original channel c = g*24 + role*8 + r
// q-role rows are p < 1152 -> contiguous; fp32-fidelity split applies there only.
// qkv, ms stored permuted and in f16.

__device__ __align__(16) f16 g_Wcat_h[(size_t)NCH3 * NC];
__device__ __align__(16) f16 g_Wcat_l[(size_t)NC * NC];
__device__ __align__(16) f16 g_WoutB_h[(size_t)NC * NC2];
__device__ __align__(16) f16 g_XT_h[(size_t)NB * NHW * NC];
__device__ __align__(16) f16 g_XT_l[(size_t)NB * NHW * NC];
__device__ __align__(16) f16 g_qkv[(size_t)NB * NCH3 * NHW];
__device__ __align__(16) f16 g_ms[(size_t)NB * NCH3 * NHW];
__device__ __align__(16) f16 g_attnT_h[(size_t)NB * NHW * NC2];
__device__ float g_part[NB * NHW];

__device__ __forceinline__ void gload16(const void* g, void* l) {
  __builtin_amdgcn_global_load_lds(
      (const __attribute__((address_space(1))) unsigned int*)g,
      (__attribute__((address_space(3))) unsigned int*)l, 16, 0, 0);
}

__device__ __forceinline__ void split_f16(float v, f16& h, f16& l) {
  h = (f16)v;
  l = (f16)((v - (float)h) * LO_SCALE);
}

// ---------- weight conversion (role-permuted rows) ----------
__global__ __launch_bounds__(256) void convert_weights(
    const float* __restrict__ wq, const float* __restrict__ wk,
    const float* __restrict__ wv, const float* __restrict__ wout) {
  size_t idx = ((size_t)blockIdx.x * 256 + threadIdx.x) * 4;
  const size_t NWC = (size_t)NCH3 * NC;
  const size_t NWO = (size_t)NC * NC2;
  if (idx < NWC) {
    int p = (int)(idx / NC);
    int kk = (int)(idx % NC);
    int role = p / 1152, w = p % 1152;
    int g = w >> 3, r = w & 7;
    int c = g * 24 + role * 8 + r;
    const float* src = (c < 1152) ? wq + (size_t)c * NC + kk
                      : (c < 2304) ? wk + (size_t)(c - 1152) * NC + kk
                                   : wv + (size_t)(c - 2304) * NC + kk;
    if (p < 1152) {
#pragma unroll
      for (int j = 0; j < 4; ++j)
        split_f16(src[j], g_Wcat_h[idx + j], g_Wcat_l[idx + j]);
    } else {
#pragma unroll
      for (int j = 0; j < 4; ++j) g_Wcat_h[idx + j] = (f16)src[j];
    }
  } else {
    size_t k = idx - NWC;
    if (k < NWO) {
      const float* src = wout + k;
#pragma unroll
      for (int j = 0; j < 4; ++j) g_WoutB_h[k + j] = (f16)src[j];
    }
  }
}

// ---------- x (B,C,HW) fp32 -> XT (B,HW,C) scaled-split f16 ----------
__global__ __launch_bounds__(256) void transpose_x(const float* __restrict__ x) {
  __shared__ float tile[32][33];
  int z = blockIdx.z;
  int p0 = blockIdx.x * 32, c0 = blockIdx.y * 32;
  int tx = threadIdx.x, ty = threadIdx.y;
#pragma unroll
  for (int i = 0; i < 32; i += 8)
    tile[ty + i][tx] = x[((size_t)z * NC + c0 + ty + i) * NHW + p0 + tx];
  __syncthreads();
#pragma unroll
  for (int i = 0; i < 32; i += 8) {
    size_t o = ((size_t)z * NHW + p0 + ty + i) * NC + c0 + tx;
    split_f16(tile[tx][ty + i], g_XT_h[o], g_XT_l[o]);
  }
}

// ===== gemm1 q-part (split-f16, fp32 fidelity): 128x256, deep 3-buf,
// one barrier per K-tile, counted vmcnt(6).
__device__ __forceinline__ void gemm1_split_deep(char* smem, int bm, int bn, int bz) {
  const int tid = threadIdx.x;
  const int lane = tid & 63;
  const int wid = tid >> 6;
  const int wr = wid >> 2, wc = wid & 3;
  const size_t boff = (size_t)bz * ((size_t)NHW * NC);
  const f16* Bh = g_XT_h + boff;
  const f16* Bl = g_XT_l + boff;
  f16* Cb = g_qkv + (size_t)bz * ((size_t)NCH3 * NHW);
  const int srow = tid >> 2;
  const int skb = (((tid & 3) ^ ((srow >> 1) & 3)) * 8);
  const f16* gAh = g_Wcat_h + (size_t)(bm + srow) * NC + skb;
  const f16* gAl = g_Wcat_l + (size_t)(bm + srow) * NC + skb;
  const f16* gBh0 = Bh + (size_t)(bn + srow) * NC + skb;
  const f16* gBl0 = Bl + (size_t)(bn + srow) * NC + skb;
  const f16* gBh1 = Bh + (size_t)(bn + 128 + srow) * NC + skb;
  const f16* gBl1 = Bl + (size_t)(bn + 128 + srow) * NC + skb;
  const int ldso = tid * 16;

  f32x16 acc[2][2] = {};
  f32x16 acc2[2][2] = {};
  const int r31 = lane & 31;
  const int key = (r31 >> 1) & 3;
  const int kblk = lane >> 5;

#define BUFS(b, off) (smem + (b) * 49152 + (off))
#define STG_S0(buf, tile)                                       \
  do {                                                          \
    size_t ko = (size_t)(tile) * 32;                            \
    gload16(gAh + ko, BUFS(buf, 0) + ldso);                     \
    gload16(gAl + ko, BUFS(buf, 8192) + ldso);                  \
    gload16(gBh0 + ko, BUFS(buf, 16384) + ldso);                \
  } while (0)
#define STG_S1(buf, tile)                                       \
  do {                                                          \
    size_t ko = (size_t)(tile) * 32;                            \
    gload16(gBh1 + ko, BUFS(buf, 24576) + ldso);                \
    gload16(gBl0 + ko, BUFS(buf, 32768) + ldso);                \
    gload16(gBl1 + ko, BUFS(buf, 40960) + ldso);                \
  } while (0)

#define FPH_S(buf, kh, STG)                                                    \
  do {                                                                         \
    STG;                                                                       \
    const int bsw = (((kh) * 2 + kblk) ^ key) * 8;                             \
    const f16* sAh = (const f16*)BUFS(buf, 0);                                 \
    const f16* sAl = (const f16*)BUFS(buf, 8192);                              \
    const f16* sBh = (const f16*)BUFS(buf, 16384);                             \
    const f16* sBl = (const f16*)BUFS(buf, 32768);                             \
    f16x8 ah[2], al[2], bh[2], bl[2];                                          \
    _Pragma("unroll") for (int mb = 0; mb < 2; ++mb) {                         \
      int ro = (wr * 64 + mb * 32 + r31) * 32 + bsw;                           \
      ah[mb] = *(const f16x8*)(sAh + ro);                                      \
      al[mb] = *(const f16x8*)(sAl + ro);                                      \
    }                                                                          \
    _Pragma("unroll") for (int nb = 0; nb < 2; ++nb) {                         \
      int ro = (wc * 64 + nb * 32 + r31) * 32 + bsw;                           \
      bh[nb] = *(const f16x8*)(sBh + ro);                                      \
      bl[nb] = *(const f16x8*)(sBl + ro);                                      \
    }                                                                          \
    __builtin_amdgcn_s_setprio(1);                                             \
    _Pragma("unroll") for (int mb = 0; mb < 2; ++mb)                           \
      _Pragma("unroll") for (int nb = 0; nb < 2; ++nb) {                       \
        acc[mb][nb]  = __builtin_amdgcn_mfma_f32_32x32x16_f16(ah[mb], bh[nb], acc[mb][nb], 0, 0, 0);  \
        acc2[mb][nb] = __builtin_amdgcn_mfma_f32_32x32x16_f16(ah[mb], bl[nb], acc2[mb][nb], 0, 0, 0); \
        acc2[mb][nb] = __builtin_amdgcn_mfma_f32_32x32x16_f16(al[mb], bh[nb], acc2[mb][nb], 0, 0, 0); \
      }                                                                        \
    __builtin_amdgcn_s_setprio(0);                                             \
  } while (0)

  const int NT = NC / 32;  // 36
  STG_S0(0, 0); STG_S1(0, 0);
  STG_S0(1, 1); STG_S1(1, 1);
  int cb = 0;
#pragma unroll 1
  for (int t = 0; t < NT - 2; ++t) {
    asm volatile("s_waitcnt vmcnt(6)" ::: "memory");
    __builtin_amdgcn_s_barrier();
    int pb = cb + 2; if (pb >= 3) pb -= 3;
    FPH_S(cb, 0, STG_S0(pb, t + 2));
    FPH_S(cb, 1, STG_S1(pb, t + 2));
    cb = (cb == 2) ? 0 : cb + 1;
  }
  asm volatile("s_waitcnt vmcnt(6)" ::: "memory");
  __builtin_amdgcn_s_barrier();
  FPH_S(cb, 0, (void)0);
  FPH_S(cb, 1, (void)0);
  cb = (cb == 2) ? 0 : cb + 1;
  asm volatile("s_waitcnt vmcnt(0)" ::: "memory");
  __builtin_amdgcn_s_barrier();
  FPH_S(cb, 0, (void)0);
  FPH_S(cb, 1, (void)0);
#undef STG_S0
#undef STG_S1
#undef FPH_S
#undef BUFS
#pragma unroll
  for (int mb = 0; mb < 2; ++mb)
#pragma unroll
    for (int nb = 0; nb < 2; ++nb) {
      int col = bn + wc * 64 + nb * 32 + r31;
#pragma unroll
      for (int reg = 0; reg < 16; ++reg) {
        int row = bm + wr * 64 + mb * 32 + (reg & 3) + 8 * (reg >> 2) + 4 * (lane >> 5);
        Cb[(size_t)row * NHW + col] = (f16)(acc[mb][nb][reg] + acc2[mb][nb][reg] * LO_INV);
      }
    }
}

// ===== gemm1 kv-part (plain f16): 128x256, deep 3-buf, 3 loads/tile, vmcnt(3)
__device__ __forceinline__ void gemm1_kv_deep(char* smem, int bmG, int bn, int bz) {
  f16* sA0 = (f16*)smem;                 // 3 x 8KB
  f16* sB0 = (f16*)(smem + 24576);       // 3 x 16KB
  const int tid = threadIdx.x;
  const int lane = tid & 63;
  const int wid = tid >> 6;
  const int wr = wid >> 2, wc = wid & 3;  // wave tile 64x64
  const f16* Bb = g_XT_h + (size_t)bz * ((size_t)NHW * NC);
  f16* Cb = g_qkv + (size_t)bz * ((size_t)NCH3 * NHW);
  const int srow = tid >> 2;
  const int skb = (((tid & 3) ^ ((srow >> 1) & 3)) * 8);
  const f16* gA0 = g_Wcat_h + (size_t)(bmG + srow) * NC + skb;
  const f16* gB0 = Bb + (size_t)(bn + srow) * NC + skb;
  const f16* gB1 = Bb + (size_t)(bn + 128 + srow) * NC + skb;
  const int ldso = tid * 16;

  f32x16 acc[2][2] = {};
  const int r31 = lane & 31;
  const int key = (r31 >> 1) & 3;
  const int kblk = lane >> 5;

#define SA(b) (sA0 + (b) * 4096)
#define SB(b) (sB0 + (b) * 8192)
#define STG_KV(buf, tile)                                       \
  do {                                                          \
    size_t ko = (size_t)(tile) * 32;                            \
    gload16(gA0 + ko, (char*)SA(buf) + ldso);                   \
    gload16(gB0 + ko, (char*)SB(buf) + ldso);                   \
    gload16(gB1 + ko, (char*)SB(buf) + 8192 + ldso);            \
  } while (0)
#define FPH_KV(buf, ks, STG)                                                   \
  do {                                                                         \
    STG;                                                                       \
    const int bsw = (((ks) * 2 + kblk) ^ key) * 8;                             \
    f16x8 af[2], bf[2];                                                        \
    _Pragma("unroll") for (int mb = 0; mb < 2; ++mb) {                         \
      int row = wr * 64 + mb * 32 + r31;                                       \
      af[mb] = *(const f16x8*)(SA(buf) + row * 32 + bsw);                      \
    }                                                                          \
    _Pragma("unroll") for (int nb = 0; nb < 2; ++nb) {                         \
      int row = wc * 64 + nb * 32 + r31;                                       \
      bf[nb] = *(const f16x8*)(SB(buf) + row * 32 + bsw);                      \
    }                                                                          \
    __builtin_amdgcn_s_setprio(1);                                             \
    _Pragma("unroll") for (int mb = 0; mb < 2; ++mb)                           \
      _Pragma("unroll") for (int nb = 0; nb < 2; ++nb)                         \
        acc[mb][nb] = __builtin_amdgcn_mfma_f32_32x32x16_f16(af[mb], bf[nb], acc[mb][nb], 0, 0, 0); \
    __builtin_amdgcn_s_setprio(0);                                             \
  } while (0)

  const int NT = NC / 32;  // 36
  STG_KV(0, 0);
  STG_KV(1, 1);
  int cb = 0;
#pragma unroll 1
  for (int t = 0; t < NT - 2; ++t) {
    asm volatile("s_waitcnt vmcnt(3)" ::: "memory");
    __builtin_amdgcn_s_barrier();
    int pb = cb + 2; if (pb >= 3) pb -= 3;
    FPH_KV(cb, 0, STG_KV(pb, t + 2));
    FPH_KV(cb, 1, (void)0);
    cb = (cb == 2) ? 0 : cb + 1;
  }
  asm volatile("s_waitcnt vmcnt(3)" ::: "memory");
  __builtin_amdgcn_s_barrier();
  FPH_KV(cb, 0, (void)0);
  FPH_KV(cb, 1, (void)0);
  cb = (cb == 2) ? 0 : cb + 1;
  asm volatile("s_waitcnt vmcnt(0)" ::: "memory");
  __builtin_amdgcn_s_barrier();
  FPH_KV(cb, 0, (void)0);
  FPH_KV(cb, 1, (void)0);
#undef STG_KV
#undef FPH_KV
#undef SA
#undef SB
#pragma unroll
  for (int mb = 0; mb < 2; ++mb)
#pragma unroll
    for (int nb = 0; nb < 2; ++nb) {
      int col = bn + wc * 64 + nb * 32 + r31;
#pragma unroll
      for (int reg = 0; reg < 16; ++reg) {
        int row = bmG + wr * 64 + mb * 32 + (reg & 3) + 8 * (reg >> 2) + 4 * (lane >> 5);
        Cb[(size_t)row * NHW + col] = (f16)acc[mb][nb][reg];
      }
    }
}

// 864 blocks. XCD-chunked: swz = (bid&7)*108 + (bid>>3) gives each XCD a
// contiguous range of 108 swz = 4 B-panels x 27 class-mixed blocks. Within
// an XCD the ~32 co-resident blocks span ~1.2 panels -> B L2-resident;
// idx (class) fastest-varying -> temporal balance of long/short blocks.
__global__ __launch_bounds__(512, 1) void gemm1_kernel() {
  __shared__ __align__(16) char smem[147456];
  int bid = blockIdx.x;
  int swz = (bid & 7) * 108 + (bid >> 3);
  int idx = swz % 27;          // 0..26 (class-mixed, fastest)
  int panel = swz / 27;        // 0..31
  int bn = (panel & 15) * 256;
  int bz = panel >> 4;
  if (idx < 9)
    gemm1_split_deep(smem, idx * 128, bn, bz);
  else
    gemm1_kv_deep(smem, 1152 + (idx - 9) * 128, bn, bz);
}

// ---------- gemm2: plain f16 (128x128, 4 waves) 2-phase depth-3 (round-16 body)
// + fused RMS partial-sum epilogue ----------
template <int M, int N, int K>
__device__ __forceinline__ void gemm_body_plain(
    const f16* __restrict__ A, const f16* __restrict__ Bt,
    float* __restrict__ C, int bm, int bn, int bz) {
  __shared__ __align__(16) f16 sA[3][128 * 32];
  __shared__ __align__(16) f16 sB[3][128 * 32];
  const int tid = threadIdx.x;
  const int lane = tid & 63;
  const int wid = tid >> 6;
  const int wr = wid >> 1, wc = wid & 1;
  const f16* Bb = Bt + (size_t)bz * ((size_t)N * K);
  float* Cb = C + (size_t)bz * ((size_t)M * N);
  const int srow = tid >> 2;
  const int skb = (((tid & 3) ^ ((srow >> 1) & 3)) * 8);
  const f16* gA0 = A + (size_t)(bm + srow) * K + skb;
  const f16* gA1 = A + (size_t)(bm + 64 + srow) * K + skb;
  const f16* gB0 = Bb + (size_t)(bn + srow) * K + skb;
  const f16* gB1 = Bb + (size_t)(bn + 64 + srow) * K + skb;
  const int ldso = tid * 16;

  f32x16 acc[2][2] = {};
  const int r31 = lane & 31;
  const int key = (r31 >> 1) & 3;
  const int kblk = lane >> 5;

#define STAGE_P(buf, tile)                              \
  do {                                                  \
    size_t ko = (size_t)(tile) * 32;                    \
    gload16(gA0 + ko, (char*)sA[buf] + ldso);           \
    gload16(gA1 + ko, (char*)sA[buf] + 4096 + ldso);    \
    gload16(gB0 + ko, (char*)sB[buf] + ldso);           \
    gload16(gB1 + ko, (char*)sB[buf] + 4096 + ldso);    \
  } while (0)

#define COMPUTE_P(buf)                                                         \
  do {                                                                         \
    _Pragma("unroll") for (int kh = 0; kh < 2; ++kh) {                         \
      const int bsw = ((kh * 2 + kblk) ^ key) * 8;                             \
      f16x8 af[2], bf[2];                                                      \
      _Pragma("unroll") for (int mb = 0; mb < 2; ++mb)                         \
        af[mb] = *(const f16x8*)(sA[buf] + (wr * 64 + mb * 32 + r31) * 32 + bsw); \
      _Pragma("unroll") for (int nb = 0; nb < 2; ++nb)                         \
        bf[nb] = *(const f16x8*)(sB[buf] + (wc * 64 + nb * 32 + r31) * 32 + bsw); \
      __builtin_amdgcn_s_setprio(1);                                           \
      _Pragma("unroll") for (int mb = 0; mb < 2; ++mb)                         \
        _Pragma("unroll") for (int nb = 0; nb < 2; ++nb)                       \
          acc[mb][nb] = __builtin_amdgcn_mfma_f32_32x32x16_f16(af[mb], bf[nb], acc[mb][nb], 0, 0, 0); \
      __builtin_amdgcn_s_setprio(0);                                           \
    }                                                                          \
  } while (0)

  const int NT = K / 32;  // 72
  STAGE_P(0, 0);
  STAGE_P(1, 1);
  int cb = 0, sb = 2;
#pragma unroll 1
  for (int t = 0; t < NT - 1; ++t) {
    asm volatile("s_waitcnt vmcnt(4)" ::: "memory");
    __builtin_amdgcn_s_barrier();
    __builtin_amdgcn_sched_barrier(0);
    if (t + 2 < NT) STAGE_P(sb, t + 2);
    COMPUTE_P(cb);
    __builtin_amdgcn_sched_barrier(0);
    __builtin_amdgcn_s_barrier();
    cb = (cb == 2) ? 0 : cb + 1;
    sb = (sb == 2) ? 0 : sb + 1;
  }
  asm volatile("s_waitcnt vmcnt(0)" ::: "memory");
  __builtin_amdgcn_s_barrier();
  __builtin_amdgcn_sched_barrier(0);
  COMPUTE_P(cb);
#undef STAGE_P
#undef COMPUTE_P
#pragma unroll
  for (int nb = 0; nb < 2; ++nb) {
    int col = bn + wc * 64 + nb * 32 + r31;
    float csum = 0.f;
#pragma unroll
    for (int mb = 0; mb < 2; ++mb)
#pragma unroll
      for (int reg = 0; reg < 16; ++reg) {
        int row = bm + wr * 64 + mb * 32 + (reg & 3) + 8 * (reg >> 2) + 4 * (lane >> 5);
        float v = acc[mb][nb][reg];
        Cb[(size_t)row * N + col] = v;
        csum += v * v;
      }
    atomicAdd(&g_part[bz * NHW + col], csum);
  }
}

__global__ __launch_bounds__(256, 2) void gemm2_kernel(float* __restrict__ out) {
  int bid = blockIdx.x;
  int swz = (bid & 7) * (576 / 8) + (bid >> 3);
  int bx = swz % 9, rem = swz / 9;
  int by = rem & 31, bz = rem >> 5;
  gemm_body_plain<NC, NHW, NC2>(g_WoutB_h, g_attnT_h, out,
                                bx * 128, by * 128, bz);
}

// ---------- fused depthwise 5x5 + grouped 1x1 (f16 io, fp32 math, 8 px/thr) ----------
__global__ __launch_bounds__(256) void conv_kernel(const float* __restrict__ wdw,
                                                   const float* __restrict__ wpw) {
  const int z = blockIdx.z, gg = blockIdx.y;  // 0..431
  const int pbase = (gg % 3) * 1152 + (gg / 3) * 8;
  const int px = blockIdx.x * 2048 + threadIdx.x * 8;
  const int h = px >> 6, w0 = px & 63;
  const f16* base = g_qkv + ((size_t)z * NCH3 + pbase) * NHW;

  float dw[8][8];
#pragma unroll
  for (int ci = 0; ci < 8; ++ci) {
    const float* wd = wdw + (gg * 8 + ci) * 25;
    const f16* srcc = base + (size_t)ci * NHW;
    float acc[8] = {};
#pragma unroll
    for (int dy = -2; dy <= 2; ++dy) {
      int hh = h + dy;
      if (hh < 0 || hh > 63) continue;
      const f16* row = srcc + hh * 64;
      f16x8 Lv = {}, Rv = {};
      if (w0 >= 8) Lv = *(const f16x8*)(row + w0 - 8);
      f16x8 Mv = *(const f16x8*)(row + w0);
      if (w0 <= 48) Rv = *(const f16x8*)(row + w0 + 8);
      float c[24];
#pragma unroll
      for (int i = 0; i < 8; ++i) {
        c[i] = (float)Lv[i];
        c[8 + i] = (float)Mv[i];
        c[16 + i] = (float)Rv[i];
      }
      const float* wrow = wd + (dy + 2) * 5;
#pragma unroll
      for (int dx = 0; dx < 5; ++dx) {
        float wv = wrow[dx];
#pragma unroll
        for (int j = 0; j < 8; ++j) acc[j] += c[6 + j + dx] * wv;
      }
    }
#pragma unroll
    for (int j = 0; j < 8; ++j) dw[ci][j] = acc[j];
  }
#pragma unroll
  for (int o = 0; o < 8; ++o) {
    const float* wp = wpw + (size_t)(gg * 8 + o) * 8;
    float out[8] = {};
#pragma unroll
    for (int i = 0; i < 8; ++i) {
      float wv = wp[i];
#pragma unroll
      for (int j = 0; j < 8; ++j) out[j] += wv * dw[i][j];
    }
    f16x8 ov;
#pragma unroll
    for (int j = 0; j < 8; ++j) ov[j] = (f16)out[j];
    *(f16x8*)(g_ms + ((size_t)z * NCH3 + pbase + o) * NHW + px) = ov;
  }
}

// ---------- linear attention per (group, batch): f16 reads, 8 px/thread ----------
__global__ __launch_bounds__(256) void attn_kernel() {
  int g = blockIdx.x;
  int z = blockIdx.y;
  int tid = threadIdx.x;
  const f16* buf = (g < 144) ? g_qkv : g_ms;
  int gq = (g < 144) ? g : g - 144;
  const f16* qp = buf + ((size_t)z * NCH3 + gq * 8) * NHW;
  const f16* kp = buf + ((size_t)z * NCH3 + 1152 + gq * 8) * NHW;
  const f16* vp = buf + ((size_t)z * NCH3 + 2304 + gq * 8) * NHW;

  float s[9][8];
#pragma unroll
  for (int d = 0; d < 9; ++d)
#pragma unroll
    for (int e = 0; e < 8; ++e) s[d][e] = 0.f;

  for (int p0 = tid * 8; p0 < NHW; p0 += 2048) {
    f16x8 kx[8], vx[8];
#pragma unroll
    for (int e = 0; e < 8; ++e) kx[e] = *(const f16x8*)(kp + (size_t)e * NHW + p0);
#pragma unroll
    for (int d = 0; d < 8; ++d) vx[d] = *(const f16x8*)(vp + (size_t)d * NHW + p0);
#pragma unroll
    for (int j = 0; j < 8; ++j) {
      float kv[8], vv[8];
#pragma unroll
      for (int e = 0; e < 8; ++e) kv[e] = fmaxf((float)kx[e][j], 0.f);
#pragma unroll
      for (int d = 0; d < 8; ++d) vv[d] = (float)vx[d][j];
#pragma unroll
      for (int e = 0; e < 8; ++e) {
#pragma unroll
        for (int d = 0; d < 8; ++d) s[d][e] += vv[d] * kv[e];
        s[8][e] += kv[e];
      }
    }
  }
#pragma unroll
  for (int d = 0; d < 9; ++d)
#pragma unroll
    for (int e = 0; e < 8; ++e) {
      float v = s[d][e];
#pragma unroll
      for (int off = 32; off > 0; off >>= 1) v += __shfl_xor(v, off, 64);
      s[d][e] = v;
    }
  __shared__ float sred[4][72];
  __shared__ float sc[72];
  int w = tid >> 6, lane = tid & 63;
  if (lane == 0) {
#pragma unroll
    for (int d = 0; d < 9; ++d)
#pragma unroll
      for (int e = 0; e < 8; ++e) sred[w][d * 8 + e] = s[d][e];
  }
  __syncthreads();
  if (tid < 72) sc[tid] = sred[0][tid] + sred[1][tid] + sred[2][tid] + sred[3][tid];
  __syncthreads();
  float scl[9][8];
#pragma unroll
  for (int d = 0; d < 9; ++d)
#pragma unroll
    for (int e = 0; e < 8; ++e) scl[d][e] = sc[d * 8 + e];

  for (int p0 = tid * 8; p0 < NHW; p0 += 2048) {
    f16x8 qx[8];
#pragma unroll
    for (int e = 0; e < 8; ++e) qx[e] = *(const f16x8*)(qp + (size_t)e * NHW + p0);
#pragma unroll
    for (int j = 0; j < 8; ++j) {
      float qv[8];
#pragma unroll
      for (int e = 0; e < 8; ++e) qv[e] = fmaxf((float)qx[e][j], 0.f);
      float o[9];
#pragma unroll
      for (int d = 0; d < 9; ++d) {
        float a = 0.f;
#pragma unroll
        for (int e = 0; e < 8; ++e) a += scl[d][e] * qv[e];
        o[d] = a;
      }
      float r = 1.f / (o[8] + 1e-15f);
      f16x8 oh;
#pragma unroll
      for (int d = 0; d < 8; ++d) oh[d] = (f16)(o[d] * r);
      *(f16x8*)(g_attnT_h + ((size_t)z * NHW + p0 + j) * NC2 + g * 8) = oh;
    }
  }
}

// ---------- RMSNorm (partial sums fused into gemm2 epilogue) ----------
__global__ __launch_bounds__(256) void rms_zero() {
  g_part[blockIdx.x * 256 + threadIdx.x] = 0.f;
}
__global__ __launch_bounds__(256) void rms_norm(float* __restrict__ y,
                                                const float* __restrict__ w,
                                                const float* __restrict__ b) {
  size_t i = ((size_t)blockIdx.x * 256 + threadIdx.x) * 4;
  float4 v = *(const float4*)(y + i);
  int p = (int)(i & (NHW - 1));
  int c = (int)((i >> 12) % NC);
  int z = (int)(i / ((size_t)NC * NHW));
  const float inv = 1.0f / NC;
  float wc = w[c], bc = b[c];
  const float* pp = &g_part[z * NHW + p];
  v.x = v.x * rsqrtf(pp[0] * inv + 1e-5f) * wc + bc;
  v.y = v.y * rsqrtf(pp[1] * inv + 1e-5f) * wc + bc;
  v.z = v.z * rsqrtf(pp[2] * inv + 1e-5f) * wc + bc;
  v.w = v.w * rsqrtf(pp[3] * inv + 1e-5f) * wc + bc;
  *(float4*)(y + i) = v;
}

extern "C" void kernel_launch(void* const* d_in, const int* in_sizes, int n_in,
                              void* d_out, int out_size, void* d_ws, size_t ws_size,
                              hipStream_t stream) {
  const float* x = (const float*)d_in[0];
  const float* wq = (const float*)d_in[1];
  const float* wk = (const float*)d_in[2];
  const float* wv = (const float*)d_in[3];
  const float* wdw = (const float*)d_in[4];
  const float* wpw = (const float*)d_in[5];
  const float* wout = (const float*)d_in[6];
  const float* rw = (const float*)d_in[7];
  const float* rb = (const float*)d_in[8];
  float* y = (float*)d_out;

  convert_weights<<<6480, 256, 0, stream>>>(wq, wk, wv, wout);
  transpose_x<<<dim3(128, 36, 2), dim3(32, 8), 0, stream>>>(x);
  gemm1_kernel<<<864, 512, 0, stream>>>();
  conv_kernel<<<dim3(2, 432, 2), 256, 0, stream>>>(wdw, wpw);
  attn_kernel<<<dim3(288, 2), 256, 0, stream>>>();
  rms_zero<<<32, 256, 0, stream>>>();
  gemm2_kernel<<<576, 256, 0, stream>>>(y);
  rms_norm<<<9216, 256, 0, stream>>>(y, rw, rb);
}